// Round 2
// baseline (319.958 us; speedup 1.0000x reference)
//
#include <hip/hip_runtime.h>
#include <hip/hip_bf16.h>

#define NN 2048
#define E_CNT 32768
#define D 256
#define H 8
#define HD 32
#define DFF 1024
#define MAXN 512
#define NCONV 20

typedef __hip_bfloat16 bf16;

struct ConvTab {
    const void* src[NCONV];
    int n[NCONV];
    int off[NCONV];          // float-element offset from conv base
};

// ---------------- block-wide reduce of two values (256 threads = 4 waves) ---
__device__ __forceinline__ void block_reduce2(float& a, float& b, float* s)
{
    int lane = threadIdx.x & 63;
    int wid  = threadIdx.x >> 6;
#pragma unroll
    for (int off = 32; off > 0; off >>= 1) {
        a += __shfl_down(a, off, 64);
        b += __shfl_down(b, off, 64);
    }
    __syncthreads();                 // protect s from previous call's reads
    if (lane == 0) { s[wid * 2] = a; s[wid * 2 + 1] = b; }
    __syncthreads();
    a = s[0] + s[2] + s[4] + s[6];
    b = s[1] + s[3] + s[5] + s[7];
}

// ---------------- K0a: dtype sniffer ----------------------------------------
// If node_feat is staged fp32, its raw uint16 stream contains mantissa-low
// words that, viewed as bf16, are huge/NaN ~46% of the time. True bf16 N(0,1)
// data never exceeds 1000. flag: 1 = fp32 staging, 0 = bf16 staging.
__global__ __launch_bounds__(256) void k_sniff(const unsigned short* __restrict__ p,
                                               int* __restrict__ flagp)
{
    int tid = threadIdx.x;
    int cnt = 0;
    for (int t = tid; t < 2048; t += 256) {
        float f = __uint_as_float(((unsigned)p[t]) << 16);
        if (!(fabsf(f) < 1000.f)) cnt++;      // big, inf, or NaN
    }
#pragma unroll
    for (int off = 32; off > 0; off >>= 1) cnt += __shfl_down(cnt, off, 64);
    __shared__ int s[4];
    if ((tid & 63) == 0) s[tid >> 6] = cnt;
    __syncthreads();
    if (tid == 0) *flagp = (s[0] + s[1] + s[2] + s[3] > 64) ? 1 : 0;
}

// ---------------- K0b: convert all float inputs to fp32 in ws ---------------
__global__ __launch_bounds__(256) void k_convert(ConvTab tab, float* __restrict__ base,
                                                 const int* __restrict__ flagp)
{
    int a = blockIdx.y;
    int n = tab.n[a];
    const void* s = tab.src[a];
    float* d = base + tab.off[a];
    int flag = *flagp;
    int idx0 = blockIdx.x * 2048 + threadIdx.x;
    if (flag) {
        const float* sf = (const float*)s;
#pragma unroll
        for (int k = 0; k < 8; k++) { int i = idx0 + k * 256; if (i < n) d[i] = sf[i]; }
    } else {
        const bf16* sb = (const bf16*)s;
#pragma unroll
        for (int k = 0; k < 8; k++) { int i = idx0 + k * 256; if (i < n) d[i] = __bfloat162float(sb[i]); }
    }
}

// ---------------- K1: Q/K/V projection, 8 rows per block ---------------------
__global__ __launch_bounds__(256) void k_qkv(
    const float* __restrict__ x,
    const float* __restrict__ Wq, const float* __restrict__ bq,
    const float* __restrict__ Wk, const float* __restrict__ bk,
    const float* __restrict__ Wv, const float* __restrict__ bv,
    float* __restrict__ Q, float* __restrict__ Kk, float* __restrict__ V)
{
    const float *W, *b; float* O;
    if (blockIdx.y == 0)      { W = Wq; b = bq; O = Q;  }
    else if (blockIdx.y == 1) { W = Wk; b = bk; O = Kk; }
    else                      { W = Wv; b = bv; O = V;  }
    int tid = threadIdx.x;
    int i0  = blockIdx.x * 8;
    __shared__ float xs[8][D];
    for (int t = tid; t < 8 * D; t += 256) xs[t >> 8][t & 255] = x[i0 * D + t];
    __syncthreads();
    float acc[8] = {0, 0, 0, 0, 0, 0, 0, 0};
    for (int k = 0; k < D; k++) {
        float w = W[k * D + tid];
#pragma unroll
        for (int r = 0; r < 8; r++) acc[r] += xs[r][k] * w;
    }
    float bb = b[tid];
#pragma unroll
    for (int r = 0; r < 8; r++) O[(i0 + r) * D + tid] = acc[r] + bb;
}

// ---------------- K2: edge bias [E,H] ---------------------------------------
__global__ __launch_bounds__(256) void k_edge(
    const float* __restrict__ ef, const float* __restrict__ We,
    const float* __restrict__ be, float* __restrict__ eb)
{
    __shared__ float w[80], bb[8];
    int tid = threadIdx.x;
    if (tid < 80) w[tid] = We[tid];
    if (tid < 8)  bb[tid] = be[tid];
    __syncthreads();
    int e = blockIdx.x * 256 + tid;
    if (e < E_CNT) {
        float v[10];
#pragma unroll
        for (int t = 0; t < 10; t++) v[t] = ef[e * 10 + t];
#pragma unroll
        for (int h = 0; h < 8; h++) {
            float s = bb[h];
#pragma unroll
            for (int t = 0; t < 10; t++) s += v[t] * w[t * 8 + h];
            eb[e * 8 + h] = s;
        }
    }
}

// ---------------- K3a: CSR over src — one block: count + scan ----------------
__global__ __launch_bounds__(1024) void k_csr(const int* __restrict__ src,
                                              int* __restrict__ offsets,
                                              int* __restrict__ cursor)
{
    __shared__ int deg[NN];
    __shared__ int s2[1024];
    int t = threadIdx.x;
    deg[t] = 0; deg[t + 1024] = 0;
    __syncthreads();
    for (int e = t; e < E_CNT; e += 1024) atomicAdd(&deg[src[e]], 1);
    __syncthreads();
    int a = deg[2 * t], b = deg[2 * t + 1];
    s2[t] = a + b;
    __syncthreads();
    for (int off = 1; off < 1024; off <<= 1) {     // Hillis-Steele inclusive
        int v = (t >= off) ? s2[t - off] : 0;
        __syncthreads();
        s2[t] += v;
        __syncthreads();
    }
    int excl = s2[t] - (a + b);
    offsets[2 * t] = excl;       offsets[2 * t + 1] = excl + a;
    cursor[2 * t]  = excl;       cursor[2 * t + 1]  = excl + a;
    if (t == 1023) offsets[NN] = s2[1023];
}

// ---------------- K3b: fill CSR + adjacency bitmap ---------------------------
__global__ __launch_bounds__(256) void k_fill(
    const int* __restrict__ src, const int* __restrict__ dst,
    int* __restrict__ cursor, int* __restrict__ adj_dst, int* __restrict__ adj_eid,
    unsigned* __restrict__ bits)
{
    int e = blockIdx.x * 256 + threadIdx.x;
    if (e < E_CNT) {
        int s = src[e], d = dst[e];
        int pos = atomicAdd(&cursor[s], 1);
        adj_dst[pos] = d; adj_eid[pos] = e;
        atomicOr(&bits[s * 64 + (d >> 5)], 1u << (d & 31));
        atomicOr(&bits[d * 64 + (s >> 5)], 1u << (s & 31));
    }
    if (e < NN) atomicOr(&bits[e * 64 + (e >> 5)], 1u << (e & 31));  // self loop
}

// ---------------- K4: sparse multi-head attention, one block per node --------
__global__ __launch_bounds__(256) void k_attn(
    const float* __restrict__ Q, const float* __restrict__ K,
    const float* __restrict__ V, const float* __restrict__ eb,
    const int* __restrict__ offsets, const int* __restrict__ adj_dst,
    const int* __restrict__ adj_eid, const unsigned* __restrict__ bits,
    float* __restrict__ attn_out)
{
    int i = blockIdx.x;
    int tid = threadIdx.x;
    __shared__ float q[D];
    __shared__ int   nbr[MAXN];
    __shared__ float sc[MAXN][8];
    __shared__ unsigned short slot[NN];
    __shared__ int   eid[MAXN];
    __shared__ int   nn_s;
    __shared__ float mh[8], lh[8];
    if (tid == 0) nn_s = 0;
    q[tid] = Q[i * D + tid];
    for (int t = tid; t < NN; t += 256) slot[t] = 0xFFFF;
    __syncthreads();
    // neighbor discovery from bitmap row
    if (tid < 64) {
        unsigned w = bits[i * 64 + tid];
        while (w) {
            int b = __ffs(w) - 1;
            w &= (w - 1);
            int j = tid * 32 + b;
            int pos = atomicAdd(&nn_s, 1);
            if (pos < MAXN) nbr[pos] = j;
        }
    }
    __syncthreads();
    int nn = min(nn_s, MAXN);
    for (int n = tid; n < nn; n += 256) { slot[nbr[n]] = (unsigned short)n; eid[n] = -1; }
    __syncthreads();
    // last-edge-wins bias id per neighbor, from this node's out-edges
    int r0 = offsets[i], r1 = offsets[i + 1];
    for (int k = r0 + tid; k < r1; k += 256) {
        int n = slot[adj_dst[k]];          // forward edge => always in nbr
        atomicMax(&eid[n], adj_eid[k]);
    }
    __syncthreads();
    // scores: one (neighbor, head) task per thread
    for (int t = tid; t < nn * 8; t += 256) {
        int n = t >> 3, h = t & 7;
        int j = nbr[n];
        const float4* kr = reinterpret_cast<const float4*>(K + j * D + h * HD);
        const float4* qr = reinterpret_cast<const float4*>(q + h * HD);
        float s = 0.f;
#pragma unroll
        for (int d4 = 0; d4 < 8; d4++) {
            float4 kv = kr[d4], qv = qr[d4];
            s += qv.x * kv.x + qv.y * kv.y + qv.z * kv.z + qv.w * kv.w;
        }
        s *= 0.17677669529663687f;   // 1/sqrt(32)
        int e = eid[n];
        if (e >= 0) s += eb[e * 8 + h];
        sc[n][h] = s;
    }
    __syncthreads();
    // per-head softmax stats
    if (tid < 8) {
        float m = -1e30f;
        for (int n = 0; n < nn; n++) m = fmaxf(m, sc[n][tid]);
        float l = 0.f;
        for (int n = 0; n < nn; n++) l += expf(sc[n][tid] - m);
        mh[tid] = m; lh[tid] = l;
    }
    __syncthreads();
    for (int t = tid; t < nn * 8; t += 256) {
        int n = t >> 3, h = t & 7;
        sc[n][h] = expf(sc[n][h] - mh[h]) / lh[h];
    }
    __syncthreads();
    // PV: thread tid owns output column tid (head = tid>>5)
    int h = tid >> 5;
    float acc = 0.f;
    for (int n = 0; n < nn; n++) acc += sc[n][h] * V[nbr[n] * D + tid];
    attn_out[i * D + tid] = acc;
}

// ---------------- K5: O-proj + residual + LN1, 8 rows per block --------------
__global__ __launch_bounds__(256) void k_oproj(
    const float* __restrict__ attn_out, const float* __restrict__ Wo,
    const float* __restrict__ bo, const float* __restrict__ x_in,
    const float* __restrict__ n1w, const float* __restrict__ n1b,
    float* __restrict__ x1)
{
    int tid = threadIdx.x;
    int i0  = blockIdx.x * 8;
    __shared__ float xs[8][D];
    __shared__ float red[8];
    for (int t = tid; t < 8 * D; t += 256) xs[t >> 8][t & 255] = attn_out[i0 * D + t];
    __syncthreads();
    float acc[8] = {0, 0, 0, 0, 0, 0, 0, 0};
    for (int k = 0; k < D; k++) {
        float w = Wo[k * D + tid];
#pragma unroll
        for (int r = 0; r < 8; r++) acc[r] += xs[r][k] * w;
    }
    float bb = bo[tid];
    float gw = n1w[tid], gb = n1b[tid];
#pragma unroll
    for (int r = 0; r < 8; r++) {
        float v = acc[r] + bb + x_in[(i0 + r) * D + tid];
        float a = v, b = v * v;
        block_reduce2(a, b, red);
        float mu  = a * (1.f / D);
        float var = b * (1.f / D) - mu * mu;
        float rs  = rsqrtf(var + 1e-5f);
        x1[(i0 + r) * D + tid] = (v - mu) * rs * gw + gb;
    }
}

// ---------------- K6: fused FFN1+ReLU+FFN2 + residual + LN2 ------------------
__global__ __launch_bounds__(256) void k_ffn(
    const float* __restrict__ x1, const float* __restrict__ W1,
    const float* __restrict__ b1, const float* __restrict__ W2,
    const float* __restrict__ b2, const float* __restrict__ n2w,
    const float* __restrict__ n2b, const int* __restrict__ flagp,
    bf16* __restrict__ outb, float* __restrict__ outf)
{
    int tid = threadIdx.x;
    int i0  = blockIdx.x * 8;
    __shared__ float xs[8][D];      // 8 KB
    __shared__ float hs[8][DFF];    // 32 KB
    __shared__ float red[8];
    int flag = *flagp;
    for (int t = tid; t < 8 * D; t += 256) xs[t >> 8][t & 255] = x1[i0 * D + t];
    __syncthreads();
    float acc[8][4] = {};
    for (int k = 0; k < D; k++) {
        float w0 = W1[k * DFF + 0 * 256 + tid];
        float w1 = W1[k * DFF + 1 * 256 + tid];
        float w2 = W1[k * DFF + 2 * 256 + tid];
        float w3 = W1[k * DFF + 3 * 256 + tid];
#pragma unroll
        for (int r = 0; r < 8; r++) {
            float xv = xs[r][k];
            acc[r][0] += xv * w0; acc[r][1] += xv * w1;
            acc[r][2] += xv * w2; acc[r][3] += xv * w3;
        }
    }
#pragma unroll
    for (int j = 0; j < 4; j++) {
        float bb = b1[j * 256 + tid];
#pragma unroll
        for (int r = 0; r < 8; r++)
            hs[r][j * 256 + tid] = fmaxf(acc[r][j] + bb, 0.f);
    }
    __syncthreads();
    float a2[8] = {0, 0, 0, 0, 0, 0, 0, 0};
    for (int k = 0; k < DFF; k++) {
        float w = W2[k * D + tid];
#pragma unroll
        for (int r = 0; r < 8; r++) a2[r] += hs[r][k] * w;
    }
    float bb = b2[tid];
    float gw = n2w[tid], gb = n2b[tid];
#pragma unroll
    for (int r = 0; r < 8; r++) {
        float v = a2[r] + bb + xs[r][tid];
        float a = v, b = v * v;
        block_reduce2(a, b, red);
        float mu  = a * (1.f / D);
        float var = b * (1.f / D) - mu * mu;
        float rs  = rsqrtf(var + 1e-5f);
        float o   = (v - mu) * rs * gw + gb;
        int idx = (i0 + r) * D + tid;
        if (flag) outf[idx] = o; else outb[idx] = __float2bfloat16(o);
    }
}

extern "C" void kernel_launch(void* const* d_in, const int* in_sizes, int n_in,
                              void* d_out, int out_size, void* d_ws, size_t ws_size,
                              hipStream_t stream)
{
    (void)n_in; (void)out_size; (void)ws_size;
    const int* src = (const int*)d_in[2];
    const int* dst = (const int*)d_in[3];

    char* ws = (char*)d_ws;
    const size_t MB = 1 << 20;
    float* conv = (float*)ws;                       // 0 .. 7MB : fp32 inputs
    int*   flagp   = (int*)(ws + 7 * MB);
    int*   offsets = (int*)(ws + 7 * MB + (4 << 10));
    int*   cursor  = (int*)(ws + 7 * MB + (16 << 10));
    int*   adj_dst = (int*)(ws + 7 * MB + (32 << 10));    // 128 KB
    int*   adj_eid = (int*)(ws + 7 * MB + (160 << 10));   // 128 KB
    unsigned* bits = (unsigned*)(ws + 7 * MB + (512 << 10)); // 512 KB -> ends 8MB
    float* Q        = (float*)(ws + 8  * MB);
    float* K        = (float*)(ws + 10 * MB);
    float* V        = (float*)(ws + 12 * MB);
    float* attn_out = (float*)(ws + 14 * MB);
    float* x1       = (float*)(ws + 16 * MB);
    float* eb       = (float*)(ws + 18 * MB);       // 1 MB -> ends 19MB

    // conversion table: all float inputs -> fp32 at conv[off]
    static const int conv_idx[NCONV] =
        {0, 1, 4, 5, 6, 7, 8, 9, 10, 11, 12, 13, 14, 15, 16, 17, 18, 19, 20, 21};
    ConvTab tab;
    int off = 0;
    int maxn = 0;
    for (int a = 0; a < NCONV; a++) {
        int gi = conv_idx[a];
        tab.src[a] = d_in[gi];
        tab.n[a]   = in_sizes[gi];
        tab.off[a] = off;
        off += (in_sizes[gi] + 255) & ~255;
        if (in_sizes[gi] > maxn) maxn = in_sizes[gi];
    }
    const float* f_node = conv + tab.off[0];
    const float* f_edge = conv + tab.off[1];
    const float* fWq = conv + tab.off[2],  *fbq = conv + tab.off[3];
    const float* fWk = conv + tab.off[4],  *fbk = conv + tab.off[5];
    const float* fWv = conv + tab.off[6],  *fbv = conv + tab.off[7];
    const float* fWo = conv + tab.off[8],  *fbo = conv + tab.off[9];
    const float* fWe = conv + tab.off[10], *fbe = conv + tab.off[11];
    const float* fn1w = conv + tab.off[12], *fn1b = conv + tab.off[13];
    const float* fW1 = conv + tab.off[14], *fb1 = conv + tab.off[15];
    const float* fW2 = conv + tab.off[16], *fb2 = conv + tab.off[17];
    const float* fn2w = conv + tab.off[18], *fn2b = conv + tab.off[19];

    hipMemsetAsync(bits, 0x00, (size_t)NN * 64 * 4, stream);

    k_sniff<<<1, 256, 0, stream>>>((const unsigned short*)d_in[0], flagp);
    dim3 cgrid((maxn + 2047) / 2048, NCONV);
    k_convert<<<cgrid, 256, 0, stream>>>(tab, conv, flagp);

    k_qkv <<<dim3(NN / 8, 3), 256, 0, stream>>>(f_node, fWq, fbq, fWk, fbk, fWv, fbv, Q, K, V);
    k_edge<<<E_CNT / 256, 256, 0, stream>>>(f_edge, fWe, fbe, eb);
    k_csr <<<1, 1024, 0, stream>>>(src, offsets, cursor);
    k_fill<<<E_CNT / 256, 256, 0, stream>>>(src, dst, cursor, adj_dst, adj_eid, bits);
    k_attn<<<NN, 256, 0, stream>>>(Q, K, V, eb, offsets, adj_dst, adj_eid, bits, attn_out);
    k_oproj<<<NN / 8, 256, 0, stream>>>(attn_out, fWo, fbo, f_node, fn1w, fn1b, x1);
    k_ffn <<<NN / 8, 256, 0, stream>>>(x1, fW1, fb1, fW2, fb2, fn2w, fn2b, flagp,
                                       (bf16*)d_out, (float*)d_out);
}

// Round 4
// 215.083 us; speedup vs baseline: 1.4876x; 1.4876x over previous
//
#include <hip/hip_runtime.h>
#include <hip/hip_bf16.h>

#define NN 2048
#define E_CNT 32768
#define D 256
#define DFF 1024
#define MAXN 512
#define NCONV 14

typedef __hip_bfloat16 bf16;
typedef __attribute__((ext_vector_type(8))) short short8;
typedef __attribute__((ext_vector_type(4))) float f32x4;

__device__ __forceinline__ short bf2s(bf16 x) { union { bf16 b; short s; } u; u.b = x; return u.s; }

struct ConvTab { const void* src[NCONV]; int n[NCONV]; int off[NCONV]; };
struct TransTab { const void* src[6]; int K[6]; int N[6]; int off[6]; };

// ---------------- K0a: dtype sniffer (bf16 vs fp32 staging) ------------------
__global__ __launch_bounds__(256) void k_sniff(const unsigned short* __restrict__ p,
                                               int* __restrict__ flagp)
{
    int tid = threadIdx.x;
    int cnt = 0;
    for (int t = tid; t < 2048; t += 256) {
        float f = __uint_as_float(((unsigned)p[t]) << 16);
        if (!(fabsf(f) < 1000.f)) cnt++;
    }
#pragma unroll
    for (int off = 32; off > 0; off >>= 1) cnt += __shfl_down(cnt, off, 64);
    __shared__ int s[4];
    if ((tid & 63) == 0) s[tid >> 6] = cnt;
    __syncthreads();
    if (tid == 0) *flagp = (s[0] + s[1] + s[2] + s[3] > 64) ? 1 : 0;
}

// ---------------- K0b: float inputs -> fp32 in ws ----------------------------
__global__ __launch_bounds__(256) void k_convert(ConvTab tab, float* __restrict__ base,
                                                 const int* __restrict__ flagp)
{
    int a = blockIdx.y;
    int n = tab.n[a];
    const void* s = tab.src[a];
    float* d = base + tab.off[a];
    int flag = *flagp;
    int idx0 = blockIdx.x * 2048 + threadIdx.x;
    if (flag) {
        const float* sf = (const float*)s;
#pragma unroll
        for (int k = 0; k < 8; k++) { int i = idx0 + k * 256; if (i < n) d[i] = sf[i]; }
    } else {
        const bf16* sb = (const bf16*)s;
#pragma unroll
        for (int k = 0; k < 8; k++) { int i = idx0 + k * 256; if (i < n) d[i] = __bfloat162float(sb[i]); }
    }
}

// ---------------- K0c: node_feat -> bf16 copy --------------------------------
__global__ __launch_bounds__(256) void k_tobf16(const void* __restrict__ src,
                                                bf16* __restrict__ dst,
                                                const int* __restrict__ flagp, int n)
{
    int flag = *flagp;
    int i0 = blockIdx.x * 2048 + threadIdx.x;
    if (flag) {
        const float* s = (const float*)src;
#pragma unroll
        for (int k = 0; k < 8; k++) { int i = i0 + k * 256; if (i < n) dst[i] = __float2bfloat16(s[i]); }
    } else {
        const short* s = (const short*)src;
        short* d = (short*)dst;
#pragma unroll
        for (int k = 0; k < 8; k++) { int i = i0 + k * 256; if (i < n) d[i] = s[i]; }
    }
}

// ---------------- K0d: transpose weights [K][N] -> bf16 [N][K] ---------------
__global__ __launch_bounds__(256) void k_trans(TransTab tab, short* __restrict__ wt,
                                               const int* __restrict__ flagp)
{
    int a = blockIdx.z;
    int Kd = tab.K[a], Nd = tab.N[a];
    int n0 = blockIdx.x * 32, k0 = blockIdx.y * 32;
    if (n0 >= Nd || k0 >= Kd) return;
    int flag = *flagp;
    __shared__ short tile[32][33];
    int t = threadIdx.x, c = t & 31, r4 = t >> 5;
    const void* s = tab.src[a];
#pragma unroll
    for (int p = 0; p < 4; p++) {
        int r = r4 + p * 8;
        short v;
        if (flag) v = bf2s(__float2bfloat16(((const float*)s)[(size_t)(k0 + r) * Nd + n0 + c]));
        else      v = ((const short*)s)[(size_t)(k0 + r) * Nd + n0 + c];
        tile[r][c] = v;
    }
    __syncthreads();
    short* dT = wt + tab.off[a];
#pragma unroll
    for (int p = 0; p < 4; p++) {
        int r = r4 + p * 8;
        dT[(size_t)(n0 + r) * Kd + k0 + c] = tile[c][r];
    }
}

// ---------------- MFMA GEMM: C[M,N] = A[M,K](bf16) @ BT[N,K]^T + bias --------
// tile 64x32, 256 threads = 4 waves; wave w does rows w*16..+16, all 32 cols.
// LDS chunk-major [kchunk][row][8] -> conflict-free ds_read_b128 frags.
template<int EPI>   // 0: fp32 out (+bias), 1: bf16 out (+bias, relu)
__global__ __launch_bounds__(256) void k_gemm(
    const bf16* __restrict__ A, const bf16* __restrict__ BT,
    const float* __restrict__ bias, void* __restrict__ Cp, int N, int K)
{
    __shared__ __align__(16) short As[4 * 64 * 8];
    __shared__ __align__(16) short Bs[4 * 32 * 8];
    int t = threadIdx.x;
    int w = t >> 6, l = t & 63;
    int fr = l & 15, fc = l >> 4;
    int i0 = blockIdx.x * 64, j0 = blockIdx.y * 32;
    int lr = t >> 2, lc = t & 3;
    f32x4 acc0 = {0.f, 0.f, 0.f, 0.f}, acc1 = {0.f, 0.f, 0.f, 0.f};
    const short* ap = (const short*)A + (size_t)(i0 + lr) * K + lc * 8;
    const short* bp = (const short*)BT + (size_t)(j0 + (lr & 31)) * K + lc * 8;
    for (int k0 = 0; k0 < K; k0 += 32) {
        short8 av = *(const short8*)(ap + k0);
        short8 bv = {};
        if (t < 128) bv = *(const short8*)(bp + k0);
        __syncthreads();
        *(short8*)&As[(lc * 64 + lr) * 8] = av;
        if (t < 128) *(short8*)&Bs[(lc * 32 + lr) * 8] = bv;
        __syncthreads();
        short8 af  = *(const short8*)&As[(fc * 64 + w * 16 + fr) * 8];
        short8 bf0 = *(const short8*)&Bs[(fc * 32 + fr) * 8];
        short8 bf1 = *(const short8*)&Bs[(fc * 32 + 16 + fr) * 8];
        acc0 = __builtin_amdgcn_mfma_f32_16x16x32_bf16(af, bf0, acc0, 0, 0, 0);
        acc1 = __builtin_amdgcn_mfma_f32_16x16x32_bf16(af, bf1, acc1, 0, 0, 0);
    }
    float bb0 = bias[j0 + fr];
    float bb1 = bias[j0 + 16 + fr];
    int orow = i0 + w * 16 + fc * 4;
    if (EPI == 0) {
        float* C = (float*)Cp;
#pragma unroll
        for (int j = 0; j < 4; j++) {
            C[(size_t)(orow + j) * N + j0 + fr]      = acc0[j] + bb0;
            C[(size_t)(orow + j) * N + j0 + 16 + fr] = acc1[j] + bb1;
        }
    } else {
        bf16* C = (bf16*)Cp;
#pragma unroll
        for (int j = 0; j < 4; j++) {
            C[(size_t)(orow + j) * N + j0 + fr]      = __float2bfloat16(fmaxf(acc0[j] + bb0, 0.f));
            C[(size_t)(orow + j) * N + j0 + 16 + fr] = __float2bfloat16(fmaxf(acc1[j] + bb1, 0.f));
        }
    }
}

// ---------------- K2: edge bias [E,H] ---------------------------------------
__global__ __launch_bounds__(256) void k_edge(
    const float* __restrict__ ef, const float* __restrict__ We,
    const float* __restrict__ be, float* __restrict__ eb)
{
    __shared__ float w[80], bb[8];
    int tid = threadIdx.x;
    if (tid < 80) w[tid] = We[tid];
    if (tid < 8)  bb[tid] = be[tid];
    __syncthreads();
    int e = blockIdx.x * 256 + tid;
    if (e < E_CNT) {
        float v[10];
#pragma unroll
        for (int t = 0; t < 10; t++) v[t] = ef[e * 10 + t];
#pragma unroll
        for (int h = 0; h < 8; h++) {
            float s = bb[h];
#pragma unroll
            for (int t = 0; t < 10; t++) s += v[t] * w[t * 8 + h];
            eb[e * 8 + h] = s;
        }
    }
}

// ---------------- K3a: CSR over src — one block: count + scan ----------------
__global__ __launch_bounds__(1024) void k_csr(const int* __restrict__ src,
                                              int* __restrict__ offsets,
                                              int* __restrict__ cursor)
{
    __shared__ int deg[NN];
    __shared__ int s2[1024];
    int t = threadIdx.x;
    deg[t] = 0; deg[t + 1024] = 0;
    __syncthreads();
    for (int e = t; e < E_CNT; e += 1024) atomicAdd(&deg[src[e]], 1);
    __syncthreads();
    int a = deg[2 * t], b = deg[2 * t + 1];
    s2[t] = a + b;
    __syncthreads();
    for (int off = 1; off < 1024; off <<= 1) {
        int v = (t >= off) ? s2[t - off] : 0;
        __syncthreads();
        s2[t] += v;
        __syncthreads();
    }
    int excl = s2[t] - (a + b);
    offsets[2 * t] = excl;       offsets[2 * t + 1] = excl + a;
    cursor[2 * t]  = excl;       cursor[2 * t + 1]  = excl + a;
    if (t == 1023) offsets[NN] = s2[1023];
}

// ---------------- K3b: fill CSR + adjacency bitmap ---------------------------
__global__ __launch_bounds__(256) void k_fill(
    const int* __restrict__ src, const int* __restrict__ dst,
    int* __restrict__ cursor, int* __restrict__ adj_dst, int* __restrict__ adj_eid,
    unsigned* __restrict__ bits)
{
    int e = blockIdx.x * 256 + threadIdx.x;
    if (e < E_CNT) {
        int s = src[e], d = dst[e];
        int pos = atomicAdd(&cursor[s], 1);
        adj_dst[pos] = d; adj_eid[pos] = e;
        atomicOr(&bits[s * 64 + (d >> 5)], 1u << (d & 31));
        atomicOr(&bits[d * 64 + (s >> 5)], 1u << (s & 31));
    }
    if (e < NN) atomicOr(&bits[e * 64 + (e >> 5)], 1u << (e & 31));
}

// ---------------- K4: sparse multi-head attention ----------------------------
__global__ __launch_bounds__(256) void k_attn(
    const float* __restrict__ Q, const float* __restrict__ K,
    const float* __restrict__ V, const float* __restrict__ eb,
    const int* __restrict__ offsets, const int* __restrict__ adj_dst,
    const int* __restrict__ adj_eid, const unsigned* __restrict__ bits,
    bf16* __restrict__ attn_out)
{
    int i = blockIdx.x;
    int tid = threadIdx.x;
    __shared__ float q[D];
    __shared__ int   nbr[MAXN];
    __shared__ float sc[MAXN][8];
    __shared__ unsigned short slot[NN];
    __shared__ int   eid[MAXN];
    __shared__ int   nn_s;
    __shared__ float mh[8], lh[8];
    if (tid == 0) nn_s = 0;
    q[tid] = Q[i * D + tid];
    for (int t = tid; t < NN; t += 256) slot[t] = 0xFFFF;
    __syncthreads();
    if (tid < 64) {
        unsigned w = bits[i * 64 + tid];
        while (w) {
            int b = __ffs(w) - 1;
            w &= (w - 1);
            int j = tid * 32 + b;
            int pos = atomicAdd(&nn_s, 1);
            if (pos < MAXN) nbr[pos] = j;
        }
    }
    __syncthreads();
    int nn = min(nn_s, MAXN);
    for (int n = tid; n < nn; n += 256) { slot[nbr[n]] = (unsigned short)n; eid[n] = -1; }
    __syncthreads();
    int r0 = offsets[i], r1 = offsets[i + 1];
    for (int k = r0 + tid; k < r1; k += 256) {
        int n = slot[adj_dst[k]];
        atomicMax(&eid[n], adj_eid[k]);
    }
    __syncthreads();
    for (int t = tid; t < nn * 8; t += 256) {
        int n = t >> 3, h = t & 7;
        int j = nbr[n];
        const float4* kr = reinterpret_cast<const float4*>(K + j * D + h * 32);
        const float4* qr = reinterpret_cast<const float4*>(q + h * 32);
        float s = 0.f;
#pragma unroll
        for (int d4 = 0; d4 < 8; d4++) {
            float4 kv = kr[d4], qv = qr[d4];
            s += qv.x * kv.x + qv.y * kv.y + qv.z * kv.z + qv.w * kv.w;
        }
        s *= 0.17677669529663687f;
        int e = eid[n];
        if (e >= 0) s += eb[e * 8 + h];
        sc[n][h] = s;
    }
    __syncthreads();
    if (tid < 8) {
        float m = -1e30f;
        for (int n = 0; n < nn; n++) m = fmaxf(m, sc[n][tid]);
        float l = 0.f;
        for (int n = 0; n < nn; n++) l += expf(sc[n][tid] - m);
        mh[tid] = m; lh[tid] = l;
    }
    __syncthreads();
    for (int t = tid; t < nn * 8; t += 256) {
        int n = t >> 3, h = t & 7;
        sc[n][h] = expf(sc[n][h] - mh[h]) / lh[h];
    }
    __syncthreads();
    int h = tid >> 5;
    float acc = 0.f;
    for (int n = 0; n < nn; n++) acc += sc[n][h] * V[nbr[n] * D + tid];
    attn_out[i * D + tid] = __float2bfloat16(acc);
}

// ---------------- LN: wave-per-row, g + res -> LN -> outputs -----------------
template<int MODE>   // 0: write xf(fp32)+xb(bf16); 1: write d_out per flag
__global__ __launch_bounds__(256) void k_ln(
    const float* __restrict__ g, const float* __restrict__ res,
    const float* __restrict__ w, const float* __restrict__ b,
    float* __restrict__ xf, bf16* __restrict__ xb, const int* __restrict__ flagp)
{
    int row = blockIdx.x * 4 + (threadIdx.x >> 6);
    int l = threadIdx.x & 63;
    size_t base = (size_t)row * D + l * 4;
    float4 gv = *(const float4*)(g + base);
    float4 rv = *(const float4*)(res + base);
    float v0 = gv.x + rv.x, v1 = gv.y + rv.y, v2 = gv.z + rv.z, v3 = gv.w + rv.w;
    float s = v0 + v1 + v2 + v3;
    float q = v0 * v0 + v1 * v1 + v2 * v2 + v3 * v3;
#pragma unroll
    for (int off = 32; off > 0; off >>= 1) {
        s += __shfl_xor(s, off, 64);
        q += __shfl_xor(q, off, 64);
    }
    float mu  = s * (1.f / D);
    float var = q * (1.f / D) - mu * mu;
    float rs  = rsqrtf(var + 1e-5f);
    float4 wv = *(const float4*)(w + l * 4);
    float4 bv = *(const float4*)(b + l * 4);
    float o0 = (v0 - mu) * rs * wv.x + bv.x;
    float o1 = (v1 - mu) * rs * wv.y + bv.y;
    float o2 = (v2 - mu) * rs * wv.z + bv.z;
    float o3 = (v3 - mu) * rs * wv.w + bv.w;
    if (MODE == 0) {
        float4 o; o.x = o0; o.y = o1; o.z = o2; o.w = o3;
        *(float4*)(xf + base) = o;
        xb[base + 0] = __float2bfloat16(o0);
        xb[base + 1] = __float2bfloat16(o1);
        xb[base + 2] = __float2bfloat16(o2);
        xb[base + 3] = __float2bfloat16(o3);
    } else {
        if (*flagp) {
            float4 o; o.x = o0; o.y = o1; o.z = o2; o.w = o3;
            *(float4*)(xf + base) = o;
        } else {
            xb[base + 0] = __float2bfloat16(o0);
            xb[base + 1] = __float2bfloat16(o1);
            xb[base + 2] = __float2bfloat16(o2);
            xb[base + 3] = __float2bfloat16(o3);
        }
    }
}

extern "C" void kernel_launch(void* const* d_in, const int* in_sizes, int n_in,
                              void* d_out, int out_size, void* d_ws, size_t ws_size,
                              hipStream_t stream)
{
    (void)n_in; (void)out_size; (void)ws_size;
    const int* src = (const int*)d_in[2];
    const int* dst = (const int*)d_in[3];

    char* ws = (char*)d_ws;
    const size_t KB = 1024;
    float*    conv     = (float*)ws;                      // fp32 inputs: 0..3.3MB
    bf16*     node_b16 = (bf16*)(ws + 3584 * KB);         // 1 MB
    short*    wt       = (short*)(ws + 4608 * KB);        // 1.5 MB transposed weights
    int*      offsets  = (int*)(ws + 6144 * KB);
    int*      cursor   = (int*)(ws + 6176 * KB);
    int*      flagp    = (int*)(ws + 6208 * KB);
    int*      adj_dst  = (int*)(ws + 6272 * KB);          // 128 KB
    int*      adj_eid  = (int*)(ws + 6400 * KB);          // 128 KB
    unsigned* bits     = (unsigned*)(ws + 6528 * KB);     // 512 KB
    float*    eb       = (float*)(ws + 7168 * KB);        // 1 MB
    float*    Q        = (float*)(ws + 8192 * KB);        // 2 MB
    float*    Kx       = (float*)(ws + 10240 * KB);       // 2 MB
    float*    V        = (float*)(ws + 12288 * KB);       // 2 MB
    bf16*     attn_out = (bf16*)(ws + 14336 * KB);        // 1 MB
    bf16*     hid      = (bf16*)(ws + 15360 * KB);        // 4 MB -> ends 19 MB
    float*    g2  = Q;                 // alias: Q dead after k_attn
    float*    x1f = Kx;                // alias: K dead after k_attn
    bf16*     x1b = (bf16*)V;          // alias: V dead after k_attn
    float*    g4  = Q;                 // alias: g2 dead after LN1

    // fp32 conversion table
    static const int conv_idx[NCONV] = {0, 1, 5, 7, 9, 11, 12, 13, 14, 15, 17, 19, 20, 21};
    ConvTab tab;
    int off = 0, maxn = 0;
    for (int a = 0; a < NCONV; a++) {
        int gi = conv_idx[a];
        tab.src[a] = d_in[gi];
        tab.n[a]   = in_sizes[gi];
        tab.off[a] = off;
        off += (in_sizes[gi] + 255) & ~255;
        if (in_sizes[gi] > maxn) maxn = in_sizes[gi];
    }
    const float* fbq  = conv + tab.off[2];
    const float* fbk  = conv + tab.off[3];
    const float* fbv  = conv + tab.off[4];
    const float* fbo  = conv + tab.off[5];
    const float* fWe  = conv + tab.off[6];
    const float* fbe  = conv + tab.off[7];
    const float* fn1w = conv + tab.off[8];
    const float* fn1b = conv + tab.off[9];
    const float* fb1  = conv + tab.off[10];
    const float* fb2  = conv + tab.off[11];
    const float* fn2w = conv + tab.off[12];
    const float* fn2b = conv + tab.off[13];
    const float* node_f32 = conv + tab.off[0];
    const float* edge_f32 = conv + tab.off[1];

    // transposed-weight table: Wq,Wk,Wv,Wo,W1,W2
    TransTab tt;
    const int widx[6] = {4, 6, 8, 10, 16, 18};
    const int wK[6] = {256, 256, 256, 256, 256, 1024};
    const int wN[6] = {256, 256, 256, 256, 1024, 256};
    const int woff[6] = {0, 65536, 131072, 196608, 262144, 524288};
    for (int a = 0; a < 6; a++) { tt.src[a] = d_in[widx[a]]; tt.K[a] = wK[a]; tt.N[a] = wN[a]; tt.off[a] = woff[a]; }
    const bf16* WqT = (const bf16*)(wt + 0);
    const bf16* WkT = (const bf16*)(wt + 65536);
    const bf16* WvT = (const bf16*)(wt + 131072);
    const bf16* WoT = (const bf16*)(wt + 196608);
    const bf16* W1T = (const bf16*)(wt + 262144);
    const bf16* W2T = (const bf16*)(wt + 524288);

    hipMemsetAsync(bits, 0x00, (size_t)NN * 64 * 4, stream);

    k_sniff<<<1, 256, 0, stream>>>((const unsigned short*)d_in[0], flagp);
    k_convert<<<dim3((maxn + 2047) / 2048, NCONV), 256, 0, stream>>>(tab, conv, flagp);
    k_tobf16<<<256, 256, 0, stream>>>(d_in[0], node_b16, flagp, NN * D);
    k_trans<<<dim3(32, 32, 6), 256, 0, stream>>>(tt, wt, flagp);

    k_edge<<<E_CNT / 256, 256, 0, stream>>>(edge_f32, fWe, fbe, eb);
    k_csr<<<1, 1024, 0, stream>>>(src, offsets, cursor);
    k_fill<<<E_CNT / 256, 256, 0, stream>>>(src, dst, cursor, adj_dst, adj_eid, bits);

    k_gemm<0><<<dim3(32, 8), 256, 0, stream>>>(node_b16, WqT, fbq, Q,  D, D);
    k_gemm<0><<<dim3(32, 8), 256, 0, stream>>>(node_b16, WkT, fbk, Kx, D, D);
    k_gemm<0><<<dim3(32, 8), 256, 0, stream>>>(node_b16, WvT, fbv, V,  D, D);

    k_attn<<<NN, 256, 0, stream>>>(Q, Kx, V, eb, offsets, adj_dst, adj_eid, bits, attn_out);

    k_gemm<0><<<dim3(32, 8), 256, 0, stream>>>(attn_out, WoT, fbo, g2, D, D);
    k_ln<0><<<NN / 4, 256, 0, stream>>>(g2, node_f32, fn1w, fn1b, x1f, x1b, flagp);

    k_gemm<1><<<dim3(32, 32), 256, 0, stream>>>(x1b, W1T, fb1, hid, DFF, D);
    k_gemm<0><<<dim3(32, 8), 256, 0, stream>>>(hid, W2T, fb2, g4, D, DFF);
    k_ln<1><<<NN / 4, 256, 0, stream>>>(g4, x1f, fn2w, fn2b, (float*)d_out, (bf16*)d_out, flagp);
}

// Round 5
// 196.398 us; speedup vs baseline: 1.6291x; 1.0951x over previous
//
#include <hip/hip_runtime.h>
#include <hip/hip_bf16.h>

#define NN 2048
#define E_CNT 32768
#define D 256
#define DFF 1024
#define MAXN 512
#define NCONV 14

typedef __hip_bfloat16 bf16;
typedef __attribute__((ext_vector_type(8))) short short8;
typedef __attribute__((ext_vector_type(4))) float f32x4;

__device__ __forceinline__ short bf2s(bf16 x) { union { bf16 b; short s; } u; u.b = x; return u.s; }
__device__ __forceinline__ float bs2f(unsigned short v) { return __uint_as_float(((unsigned)v) << 16); }

struct ConvTab { const void* src[NCONV]; int n[NCONV]; int off[NCONV]; };
struct TransTab { const void* src[6]; int K[6]; int N[6]; int off[6]; };

// ---------------- K_pre: block 0 = CSR(count+scan), block 1 = dtype sniffer --
__global__ __launch_bounds__(1024) void k_pre(const int* __restrict__ src,
                                              int* __restrict__ offsets,
                                              int* __restrict__ cursor,
                                              const unsigned short* __restrict__ nodesrc,
                                              int* __restrict__ flagp)
{
    __shared__ int deg[NN];
    __shared__ int s2[1024];
    __shared__ int sn[4];
    int t = threadIdx.x;
    if (blockIdx.x == 1) {
        // sniffer: fp32-staged data viewed as bf16 words is huge/NaN ~46% of the time
        if (t < 256) {
            int cnt = 0;
            for (int i = t; i < 2048; i += 256) {
                float f = __uint_as_float(((unsigned)nodesrc[i]) << 16);
                if (!(fabsf(f) < 1000.f)) cnt++;
            }
#pragma unroll
            for (int off = 32; off > 0; off >>= 1) cnt += __shfl_down(cnt, off, 64);
            if ((t & 63) == 0) sn[t >> 6] = cnt;
        }
        __syncthreads();
        if (t == 0) *flagp = (sn[0] + sn[1] + sn[2] + sn[3] > 64) ? 1 : 0;
        return;
    }
    deg[t] = 0; deg[t + 1024] = 0;
    __syncthreads();
    for (int e = t; e < E_CNT; e += 1024) atomicAdd(&deg[src[e]], 1);
    __syncthreads();
    int a = deg[2 * t], b = deg[2 * t + 1];
    s2[t] = a + b;
    __syncthreads();
    for (int off = 1; off < 1024; off <<= 1) {
        int v = (t >= off) ? s2[t - off] : 0;
        __syncthreads();
        s2[t] += v;
        __syncthreads();
    }
    int excl = s2[t] - (a + b);
    offsets[2 * t] = excl;       offsets[2 * t + 1] = excl + a;
    cursor[2 * t]  = excl;       cursor[2 * t + 1]  = excl + a;
    if (t == 1023) offsets[NN] = s2[1023];
}

// ---------------- K_convert: float inputs -> fp32 ws; entry NCONV = node->bf16
__global__ __launch_bounds__(256) void k_convert(ConvTab tab, float* __restrict__ base,
                                                 bf16* __restrict__ nb,
                                                 const void* __restrict__ nodesrc,
                                                 const int* __restrict__ flagp)
{
    int a = blockIdx.y;
    int flag = *flagp;
    int idx0 = blockIdx.x * 2048 + threadIdx.x;
    if (a == NCONV) {
        const int n = NN * D;
        if (flag) {
            const float* s = (const float*)nodesrc;
#pragma unroll
            for (int k = 0; k < 8; k++) { int i = idx0 + k * 256; if (i < n) nb[i] = __float2bfloat16(s[i]); }
        } else {
            const short* s = (const short*)nodesrc;
            short* d = (short*)nb;
#pragma unroll
            for (int k = 0; k < 8; k++) { int i = idx0 + k * 256; if (i < n) d[i] = s[i]; }
        }
        return;
    }
    int n = tab.n[a];
    const void* s = tab.src[a];
    float* d = base + tab.off[a];
    if (flag) {
        const float* sf = (const float*)s;
#pragma unroll
        for (int k = 0; k < 8; k++) { int i = idx0 + k * 256; if (i < n) d[i] = sf[i]; }
    } else {
        const bf16* sb = (const bf16*)s;
#pragma unroll
        for (int k = 0; k < 8; k++) { int i = idx0 + k * 256; if (i < n) d[i] = __bfloat162float(sb[i]); }
    }
}

// ---------------- K_trans: weights [K][N] -> bf16 [N][K] ---------------------
__global__ __launch_bounds__(256) void k_trans(TransTab tab, short* __restrict__ wt,
                                               const int* __restrict__ flagp)
{
    int a = blockIdx.z;
    int Kd = tab.K[a], Nd = tab.N[a];
    int n0 = blockIdx.x * 32, k0 = blockIdx.y * 32;
    if (n0 >= Nd || k0 >= Kd) return;
    int flag = *flagp;
    __shared__ short tile[32][33];
    int t = threadIdx.x, c = t & 31, r4 = t >> 5;
    const void* s = tab.src[a];
#pragma unroll
    for (int p = 0; p < 4; p++) {
        int r = r4 + p * 8;
        short v;
        if (flag) v = bf2s(__float2bfloat16(((const float*)s)[(size_t)(k0 + r) * Nd + n0 + c]));
        else      v = ((const short*)s)[(size_t)(k0 + r) * Nd + n0 + c];
        tile[r][c] = v;
    }
    __syncthreads();
    short* dT = wt + tab.off[a];
#pragma unroll
    for (int p = 0; p < 4; p++) {
        int r = r4 + p * 8;
        dT[(size_t)(n0 + r) * Kd + k0 + c] = tile[c][r];
    }
}

// ---------------- K_fill_edge: y=0 CSR-fill+bitmap, y=1 edge bias ------------
__global__ __launch_bounds__(256) void k_fill_edge(
    const int* __restrict__ src, const int* __restrict__ dst,
    int* __restrict__ cursor, int* __restrict__ adj_dst, int* __restrict__ adj_eid,
    unsigned* __restrict__ bits,
    const float* __restrict__ ef, const float* __restrict__ We,
    const float* __restrict__ be, float* __restrict__ ebuf)
{
    __shared__ float w[80], bb[8];
    int tid = threadIdx.x;
    int e = blockIdx.x * 256 + tid;
    if (blockIdx.y == 0) {
        if (e < E_CNT) {
            int s = src[e], d = dst[e];
            int pos = atomicAdd(&cursor[s], 1);
            adj_dst[pos] = d; adj_eid[pos] = e;
            atomicOr(&bits[s * 64 + (d >> 5)], 1u << (d & 31));
            atomicOr(&bits[d * 64 + (s >> 5)], 1u << (s & 31));
        }
        if (e < NN) atomicOr(&bits[e * 64 + (e >> 5)], 1u << (e & 31));
        return;
    }
    if (tid < 80) w[tid] = We[tid];
    if (tid < 8)  bb[tid] = be[tid];
    __syncthreads();
    if (e < E_CNT) {
        float v[10];
#pragma unroll
        for (int t2 = 0; t2 < 10; t2++) v[t2] = ef[e * 10 + t2];
#pragma unroll
        for (int h = 0; h < 8; h++) {
            float s = bb[h];
#pragma unroll
            for (int t2 = 0; t2 < 10; t2++) s += v[t2] * w[t2 * 8 + h];
            ebuf[e * 8 + h] = s;
        }
    }
}

// ---------------- K_qkv3: 3 projections in one launch (z selects) ------------
// tile 64x32; z=0 -> Q fp32, z=1 -> K bf16, z=2 -> V bf16
__global__ __launch_bounds__(256) void k_qkv3(
    const bf16* __restrict__ A,
    const bf16* __restrict__ WqT, const bf16* __restrict__ WkT, const bf16* __restrict__ WvT,
    const float* __restrict__ bq, const float* __restrict__ bk, const float* __restrict__ bv,
    float* __restrict__ Qo, bf16* __restrict__ Kb, bf16* __restrict__ Vb)
{
    int z = blockIdx.z;
    const bf16* BT = (z == 0) ? WqT : (z == 1) ? WkT : WvT;
    const float* bias = (z == 0) ? bq : (z == 1) ? bk : bv;
    __shared__ __align__(16) short As[4 * 64 * 8];
    __shared__ __align__(16) short Bs[4 * 32 * 8];
    int t = threadIdx.x, w = t >> 6, l = t & 63, fr = l & 15, fc = l >> 4;
    int i0 = blockIdx.x * 64, j0 = blockIdx.y * 32;
    int lr = t >> 2, lc = t & 3;
    f32x4 acc0 = {0.f, 0.f, 0.f, 0.f}, acc1 = {0.f, 0.f, 0.f, 0.f};
    const short* ap = (const short*)A + (size_t)(i0 + lr) * D + lc * 8;
    const short* bp = (const short*)BT + (size_t)(j0 + (lr & 31)) * D + lc * 8;
    for (int k0 = 0; k0 < D; k0 += 32) {
        short8 av = *(const short8*)(ap + k0);
        short8 bv2 = {};
        if (t < 128) bv2 = *(const short8*)(bp + k0);
        __syncthreads();
        *(short8*)&As[(lc * 64 + lr) * 8] = av;
        if (t < 128) *(short8*)&Bs[(lc * 32 + lr) * 8] = bv2;
        __syncthreads();
        short8 af  = *(const short8*)&As[(fc * 64 + w * 16 + fr) * 8];
        short8 bf0 = *(const short8*)&Bs[(fc * 32 + fr) * 8];
        short8 bf1 = *(const short8*)&Bs[(fc * 32 + 16 + fr) * 8];
        acc0 = __builtin_amdgcn_mfma_f32_16x16x32_bf16(af, bf0, acc0, 0, 0, 0);
        acc1 = __builtin_amdgcn_mfma_f32_16x16x32_bf16(af, bf1, acc1, 0, 0, 0);
    }
    float bb0 = bias[j0 + fr], bb1 = bias[j0 + 16 + fr];
    int orow = i0 + w * 16 + fc * 4;
    if (z == 0) {
#pragma unroll
        for (int j = 0; j < 4; j++) {
            Qo[(size_t)(orow + j) * D + j0 + fr]      = acc0[j] + bb0;
            Qo[(size_t)(orow + j) * D + j0 + 16 + fr] = acc1[j] + bb1;
        }
    } else {
        bf16* C = (z == 1) ? Kb : Vb;
#pragma unroll
        for (int j = 0; j < 4; j++) {
            C[(size_t)(orow + j) * D + j0 + fr]      = __float2bfloat16(acc0[j] + bb0);
            C[(size_t)(orow + j) * D + j0 + 16 + fr] = __float2bfloat16(acc1[j] + bb1);
        }
    }
}

// ---------------- generic MFMA GEMM (used for FFN1), bf16-relu epilogue ------
template<int EPI>
__global__ __launch_bounds__(256) void k_gemm(
    const bf16* __restrict__ A, const bf16* __restrict__ BT,
    const float* __restrict__ bias, void* __restrict__ Cp, int N, int K)
{
    __shared__ __align__(16) short As[4 * 64 * 8];
    __shared__ __align__(16) short Bs[4 * 32 * 8];
    int t = threadIdx.x;
    int w = t >> 6, l = t & 63;
    int fr = l & 15, fc = l >> 4;
    int i0 = blockIdx.x * 64, j0 = blockIdx.y * 32;
    int lr = t >> 2, lc = t & 3;
    f32x4 acc0 = {0.f, 0.f, 0.f, 0.f}, acc1 = {0.f, 0.f, 0.f, 0.f};
    const short* ap = (const short*)A + (size_t)(i0 + lr) * K + lc * 8;
    const short* bp = (const short*)BT + (size_t)(j0 + (lr & 31)) * K + lc * 8;
    for (int k0 = 0; k0 < K; k0 += 32) {
        short8 av = *(const short8*)(ap + k0);
        short8 bv = {};
        if (t < 128) bv = *(const short8*)(bp + k0);
        __syncthreads();
        *(short8*)&As[(lc * 64 + lr) * 8] = av;
        if (t < 128) *(short8*)&Bs[(lc * 32 + lr) * 8] = bv;
        __syncthreads();
        short8 af  = *(const short8*)&As[(fc * 64 + w * 16 + fr) * 8];
        short8 bf0 = *(const short8*)&Bs[(fc * 32 + fr) * 8];
        short8 bf1 = *(const short8*)&Bs[(fc * 32 + 16 + fr) * 8];
        acc0 = __builtin_amdgcn_mfma_f32_16x16x32_bf16(af, bf0, acc0, 0, 0, 0);
        acc1 = __builtin_amdgcn_mfma_f32_16x16x32_bf16(af, bf1, acc1, 0, 0, 0);
    }
    float bb0 = bias[j0 + fr];
    float bb1 = bias[j0 + 16 + fr];
    int orow = i0 + w * 16 + fc * 4;
    bf16* C = (bf16*)Cp;
#pragma unroll
    for (int j = 0; j < 4; j++) {
        C[(size_t)(orow + j) * N + j0 + fr]      = __float2bfloat16(fmaxf(acc0[j] + bb0, 0.f));
        C[(size_t)(orow + j) * N + j0 + 16 + fr] = __float2bfloat16(fmaxf(acc1[j] + bb1, 0.f));
    }
}

// ---------------- K_attn: sparse multi-head attention (bf16 K/V) -------------
__global__ __launch_bounds__(256) void k_attn(
    const float* __restrict__ Q, const bf16* __restrict__ K,
    const bf16* __restrict__ V, const float* __restrict__ eb,
    const int* __restrict__ offsets, const int* __restrict__ adj_dst,
    const int* __restrict__ adj_eid, const unsigned* __restrict__ bits,
    bf16* __restrict__ attn_out)
{
    int i = blockIdx.x;
    int tid = threadIdx.x;
    __shared__ float q[D];
    __shared__ int   nbr[MAXN];
    __shared__ float sc[MAXN][8];
    __shared__ unsigned short slot[NN];
    __shared__ int   eid[MAXN];
    __shared__ int   nn_s;
    __shared__ float mh[8], lh[8];
    if (tid == 0) nn_s = 0;
    q[tid] = Q[i * D + tid];
    for (int t = tid; t < NN; t += 256) slot[t] = 0xFFFF;
    __syncthreads();
    if (tid < 64) {
        unsigned w = bits[i * 64 + tid];
        while (w) {
            int b = __ffs(w) - 1;
            w &= (w - 1);
            int j = tid * 32 + b;
            int pos = atomicAdd(&nn_s, 1);
            if (pos < MAXN) nbr[pos] = j;
        }
    }
    __syncthreads();
    int nn = min(nn_s, MAXN);
    for (int n = tid; n < nn; n += 256) { slot[nbr[n]] = (unsigned short)n; eid[n] = -1; }
    __syncthreads();
    int r0 = offsets[i], r1 = offsets[i + 1];
    for (int k = r0 + tid; k < r1; k += 256) {
        int n = slot[adj_dst[k]];
        atomicMax(&eid[n], adj_eid[k]);
    }
    __syncthreads();
    // scores: (neighbor, head) per thread; K rows bf16
    const short* Ks = (const short*)K;
    for (int t = tid; t < nn * 8; t += 256) {
        int n = t >> 3, h = t & 7;
        int j = nbr[n];
        const short8* kr = (const short8*)(Ks + (size_t)j * D + h * 32);
        const float4* qr = (const float4*)(q + h * 32);
        float s = 0.f;
#pragma unroll
        for (int c = 0; c < 4; c++) {
            short8 kv = kr[c];
            float4 q0 = qr[c * 2], q1 = qr[c * 2 + 1];
            s += q0.x * bs2f((unsigned short)kv[0]) + q0.y * bs2f((unsigned short)kv[1])
               + q0.z * bs2f((unsigned short)kv[2]) + q0.w * bs2f((unsigned short)kv[3])
               + q1.x * bs2f((unsigned short)kv[4]) + q1.y * bs2f((unsigned short)kv[5])
               + q1.z * bs2f((unsigned short)kv[6]) + q1.w * bs2f((unsigned short)kv[7]);
        }
        s *= 0.17677669529663687f;
        int e = eid[n];
        if (e >= 0) s += eb[e * 8 + h];
        sc[n][h] = s;
    }
    __syncthreads();
    // wave-parallel softmax stats: head h = tid&7, 8 lanes stride the neighbors
    if (tid < 64) {
        int h = tid & 7, n0 = tid >> 3;
        float m = -1e30f;
        for (int n = n0; n < nn; n += 8) m = fmaxf(m, sc[n][h]);
#pragma unroll
        for (int off = 8; off < 64; off <<= 1) m = fmaxf(m, __shfl_xor(m, off, 64));
        float l = 0.f;
        for (int n = n0; n < nn; n += 8) l += expf(sc[n][h] - m);
#pragma unroll
        for (int off = 8; off < 64; off <<= 1) l += __shfl_xor(l, off, 64);
        if (tid < 8) { mh[h] = m; lh[h] = 1.f / l; }
    }
    __syncthreads();
    for (int t = tid; t < nn * 8; t += 256) {
        int n = t >> 3, h = t & 7;
        sc[n][h] = expf(sc[n][h] - mh[h]) * lh[h];
    }
    __syncthreads();
    // PV: thread owns output column tid, unroll x4; V bf16
    int h = tid >> 5;
    const unsigned short* Vu = (const unsigned short*)V;
    float acc = 0.f;
    int n = 0;
    for (; n + 4 <= nn; n += 4) {
        int j0 = nbr[n], j1 = nbr[n + 1], j2 = nbr[n + 2], j3 = nbr[n + 3];
        float p0 = sc[n][h], p1 = sc[n + 1][h], p2 = sc[n + 2][h], p3 = sc[n + 3][h];
        float v0 = bs2f(Vu[(size_t)j0 * D + tid]);
        float v1 = bs2f(Vu[(size_t)j1 * D + tid]);
        float v2 = bs2f(Vu[(size_t)j2 * D + tid]);
        float v3 = bs2f(Vu[(size_t)j3 * D + tid]);
        acc += p0 * v0 + p1 * v1 + p2 * v2 + p3 * v3;
    }
    for (; n < nn; n++) acc += sc[n][h] * bs2f(Vu[(size_t)nbr[n] * D + tid]);
    attn_out[i * D + tid] = __float2bfloat16(acc);
}

// ---------------- K_gemmln: C = A@BT + bias; v = C + res; LayerNorm ----------
// 32 rows x 256 cols per block, grid 64. MODE 0: write outf+outb (x1);
// MODE 1: write d_out (fp32 or bf16 per flag).
template<int MODE, int KDIM>
__global__ __launch_bounds__(256) void k_gemmln(
    const bf16* __restrict__ A, const bf16* __restrict__ BT,
    const float* __restrict__ bias, const float* __restrict__ res,
    const float* __restrict__ lnw, const float* __restrict__ lnb,
    float* __restrict__ outf, bf16* __restrict__ outb, const int* __restrict__ flagp)
{
    __shared__ __align__(16) short As[4 * 32 * 8];     // 2 KB
    __shared__ __align__(16) short Bs[4 * 256 * 8];    // 16 KB
    __shared__ float Cs[32][257];                      // 32.9 KB
    int t = threadIdx.x;
    int w = t >> 6, l = t & 63, fr = l & 15, fc = l >> 4;
    int i0 = blockIdx.x * 32;
    int ar = t >> 2, akc = t & 3;
    f32x4 acc[2][4];
#pragma unroll
    for (int rt = 0; rt < 2; rt++)
#pragma unroll
        for (int c = 0; c < 4; c++) acc[rt][c] = {0.f, 0.f, 0.f, 0.f};
    const short* ap = (const short*)A + (size_t)(i0 + (ar & 31)) * KDIM + akc * 8;
    const short* bp = (const short*)BT;
    // register prefetch of first chunk
    short8 av = {};
    if (t < 128) av = *(const short8*)(ap);
    short8 bv[4];
#pragma unroll
    for (int p = 0; p < 4; p++)
        bv[p] = *(const short8*)(bp + (size_t)(p * 64 + ar) * KDIM + akc * 8);
    for (int k0 = 0; k0 < KDIM; k0 += 32) {
        __syncthreads();
        if (t < 128) *(short8*)&As[(akc * 32 + ar) * 8] = av;
#pragma unroll
        for (int p = 0; p < 4; p++)
            *(short8*)&Bs[(akc * 256 + p * 64 + ar) * 8] = bv[p];
        __syncthreads();
        if (k0 + 32 < KDIM) {
            if (t < 128) av = *(const short8*)(ap + k0 + 32);
#pragma unroll
            for (int p = 0; p < 4; p++)
                bv[p] = *(const short8*)(bp + (size_t)(p * 64 + ar) * KDIM + k0 + 32 + akc * 8);
        }
        short8 af0 = *(const short8*)&As[(fc * 32 + fr) * 8];
        short8 af1 = *(const short8*)&As[(fc * 32 + 16 + fr) * 8];
#pragma unroll
        for (int c = 0; c < 4; c++) {
            int ct = w * 4 + c;
            short8 bfr = *(const short8*)&Bs[(fc * 256 + ct * 16 + fr) * 8];
            acc[0][c] = __builtin_amdgcn_mfma_f32_16x16x32_bf16(af0, bfr, acc[0][c], 0, 0, 0);
            acc[1][c] = __builtin_amdgcn_mfma_f32_16x16x32_bf16(af1, bfr, acc[1][c], 0, 0, 0);
        }
    }
#pragma unroll
    for (int rt = 0; rt < 2; rt++)
#pragma unroll
        for (int c = 0; c < 4; c++) {
            int ct = w * 4 + c;
            float bb = bias[ct * 16 + fr];
#pragma unroll
            for (int j = 0; j < 4; j++)
                Cs[rt * 16 + fc * 4 + j][ct * 16 + fr] = acc[rt][c][j] + bb;
        }
    __syncthreads();
    // LN: row r = t>>3, 8 lanes per row, cols c0+8m
    int r = t >> 3, c0 = t & 7;
    float vbuf[32];
    float s = 0.f, qq = 0.f;
#pragma unroll
    for (int m = 0; m < 32; m++) {
        int c = c0 + m * 8;
        float v = Cs[r][c] + res[(size_t)(i0 + r) * D + c];
        vbuf[m] = v;
        s += v; qq += v * v;
    }
#pragma unroll
    for (int off = 1; off < 8; off <<= 1) {
        s  += __shfl_xor(s, off, 64);
        qq += __shfl_xor(qq, off, 64);
    }
    float mu  = s * (1.f / D);
    float var = qq * (1.f / D) - mu * mu;
    float rsd = rsqrtf(var + 1e-5f);
    int flag = (MODE == 1) ? *flagp : 0;
#pragma unroll
    for (int m = 0; m < 32; m++) {
        int c = c0 + m * 8;
        float o = (vbuf[m] - mu) * rsd * lnw[c] + lnb[c];
        size_t idx = (size_t)(i0 + r) * D + c;
        if (MODE == 0) {
            outf[idx] = o;
            outb[idx] = __float2bfloat16(o);
        } else {
            if (flag) outf[idx] = o;
            else      outb[idx] = __float2bfloat16(o);
        }
    }
}

extern "C" void kernel_launch(void* const* d_in, const int* in_sizes, int n_in,
                              void* d_out, int out_size, void* d_ws, size_t ws_size,
                              hipStream_t stream)
{
    (void)n_in; (void)out_size; (void)ws_size;
    const int* src = (const int*)d_in[2];
    const int* dst = (const int*)d_in[3];

    char* ws = (char*)d_ws;
    const size_t KB = 1024;
    float*    conv     = (float*)ws;                      // 0 .. 3.5 MB fp32 inputs
    bf16*     node_b16 = (bf16*)(ws + 3584 * KB);         // 1 MB
    short*    wt       = (short*)(ws + 4608 * KB);        // 1.5 MB transposed weights
    int*      offsets  = (int*)(ws + 6144 * KB);
    int*      cursor   = (int*)(ws + 6176 * KB);
    int*      flagp    = (int*)(ws + 6208 * KB);
    int*      adj_dst  = (int*)(ws + 6272 * KB);          // 128 KB
    int*      adj_eid  = (int*)(ws + 6400 * KB);          // 128 KB
    unsigned* bits     = (unsigned*)(ws + 6528 * KB);     // 512 KB
    float*    eb       = (float*)(ws + 7168 * KB);        // 1 MB
    float*    Q        = (float*)(ws + 8192 * KB);        // 2 MB
    bf16*     Kb       = (bf16*)(ws + 10240 * KB);        // 1 MB
    bf16*     Vb       = (bf16*)(ws + 11264 * KB);        // 1 MB
    bf16*     attn_out = (bf16*)(ws + 12288 * KB);        // 1 MB
    float*    x1f      = (float*)(ws + 13312 * KB);       // 2 MB
    bf16*     x1b      = (bf16*)(ws + 15360 * KB);        // 1 MB
    bf16*     hid      = (bf16*)(ws + 16384 * KB);        // 4 MB -> ends 20 MB

    // fp32 conversion table
    static const int conv_idx[NCONV] = {0, 1, 5, 7, 9, 11, 12, 13, 14, 15, 17, 19, 20, 21};
    ConvTab tab;
    int off = 0;
    for (int a = 0; a < NCONV; a++) {
        int gi = conv_idx[a];
        tab.src[a] = d_in[gi];
        tab.n[a]   = in_sizes[gi];
        tab.off[a] = off;
        off += (in_sizes[gi] + 255) & ~255;
    }
    const float* node_f32 = conv + tab.off[0];
    const float* edge_f32 = conv + tab.off[1];
    const float* fbq  = conv + tab.off[2];
    const float* fbk  = conv + tab.off[3];
    const float* fbv  = conv + tab.off[4];
    const float* fbo  = conv + tab.off[5];
    const float* fWe  = conv + tab.off[6];
    const float* fbe  = conv + tab.off[7];
    const float* fn1w = conv + tab.off[8];
    const float* fn1b = conv + tab.off[9];
    const float* fb1  = conv + tab.off[10];
    const float* fb2  = conv + tab.off[11];
    const float* fn2w = conv + tab.off[12];
    const float* fn2b = conv + tab.off[13];

    // transposed weights: Wq,Wk,Wv,Wo,W1,W2
    TransTab tt;
    const int widx[6] = {4, 6, 8, 10, 16, 18};
    const int wK[6] = {256, 256, 256, 256, 256, 1024};
    const int wN[6] = {256, 256, 256, 256, 1024, 256};
    const int woff[6] = {0, 65536, 131072, 196608, 262144, 524288};
    for (int a = 0; a < 6; a++) { tt.src[a] = d_in[widx[a]]; tt.K[a] = wK[a]; tt.N[a] = wN[a]; tt.off[a] = woff[a]; }
    const bf16* WqT = (const bf16*)(wt + 0);
    const bf16* WkT = (const bf16*)(wt + 65536);
    const bf16* WvT = (const bf16*)(wt + 131072);
    const bf16* WoT = (const bf16*)(wt + 196608);
    const bf16* W1T = (const bf16*)(wt + 262144);
    const bf16* W2T = (const bf16*)(wt + 524288);

    hipMemsetAsync(bits, 0x00, (size_t)NN * 64 * 4, stream);

    k_pre<<<2, 1024, 0, stream>>>(src, offsets, cursor, (const unsigned short*)d_in[0], flagp);
    k_convert<<<dim3(256, NCONV + 1), 256, 0, stream>>>(tab, conv, node_b16, d_in[0], flagp);
    k_trans<<<dim3(32, 32, 6), 256, 0, stream>>>(tt, wt, flagp);
    k_fill_edge<<<dim3(128, 2), 256, 0, stream>>>(src, dst, cursor, adj_dst, adj_eid, bits,
                                                  edge_f32, fWe, fbe, eb);
    k_qkv3<<<dim3(32, 8, 3), 256, 0, stream>>>(node_b16, WqT, WkT, WvT, fbq, fbk, fbv, Q, Kb, Vb);
    k_attn<<<NN, 256, 0, stream>>>(Q, Kb, Vb, eb, offsets, adj_dst, adj_eid, bits, attn_out);
    k_gemmln<0, 256><<<64, 256, 0, stream>>>(attn_out, WoT, fbo, node_f32, fn1w, fn1b,
                                             x1f, x1b, flagp);
    k_gemm<1><<<dim3(32, 32), 256, 0, stream>>>(x1b, W1T, fb1, hid, DFF, D);
    k_gemmln<1, 1024><<<64, 256, 0, stream>>>(hid, W2T, fb2, x1f, fn2w, fn2b,
                                              (float*)d_out, (bf16*)d_out, flagp);
}

// Round 6
// 188.496 us; speedup vs baseline: 1.6974x; 1.0419x over previous
//
#include <hip/hip_runtime.h>
#include <hip/hip_bf16.h>

#define NN 2048
#define E_CNT 32768
#define D 256
#define DFF 1024
#define MAXN 256
#define NCONV 14

typedef __hip_bfloat16 bf16;
typedef __attribute__((ext_vector_type(8))) short short8;
typedef __attribute__((ext_vector_type(4))) float f32x4;

__device__ __forceinline__ short bf2s(bf16 x) { union { bf16 b; short s; } u; u.b = x; return u.s; }
__device__ __forceinline__ float bs2f(unsigned short v) { return __uint_as_float(((unsigned)v) << 16); }
__device__ __forceinline__ short f2bs(float f) { union { bf16 b; short s; } u; u.b = __float2bfloat16(f); return u.s; }

struct ConvTab { const void* src[NCONV]; int n[NCONV]; int off[NCONV]; };
struct TransTab { const void* src[6]; int K[6]; int N[6]; int off[6]; };

// ---------------- K_sniff: bf16 vs fp32 staging detector ---------------------
__global__ __launch_bounds__(256) void k_sniff(const unsigned short* __restrict__ p,
                                               int* __restrict__ flagp)
{
    int tid = threadIdx.x;
    int cnt = 0;
    for (int t = tid; t < 2048; t += 256) {
        float f = __uint_as_float(((unsigned)p[t]) << 16);
        if (!(fabsf(f) < 1000.f)) cnt++;
    }
#pragma unroll
    for (int off = 32; off > 0; off >>= 1) cnt += __shfl_down(cnt, off, 64);
    __shared__ int s[4];
    if ((tid & 63) == 0) s[tid >> 6] = cnt;
    __syncthreads();
    if (tid == 0) *flagp = (s[0] + s[1] + s[2] + s[3] > 64) ? 1 : 0;
}

// ---------------- K_convert: float inputs -> fp32 ws; entry NCONV = node->bf16
__global__ __launch_bounds__(256) void k_convert(ConvTab tab, float* __restrict__ base,
                                                 bf16* __restrict__ nb,
                                                 const void* __restrict__ nodesrc,
                                                 const int* __restrict__ flagp)
{
    int a = blockIdx.y;
    int flag = *flagp;
    int idx0 = blockIdx.x * 2048 + threadIdx.x;
    if (a == NCONV) {
        const int n = NN * D;
        if (flag) {
            const float* s = (const float*)nodesrc;
#pragma unroll
            for (int k = 0; k < 8; k++) { int i = idx0 + k * 256; if (i < n) nb[i] = __float2bfloat16(s[i]); }
        } else {
            const short* s = (const short*)nodesrc;
            short* d = (short*)nb;
#pragma unroll
            for (int k = 0; k < 8; k++) { int i = idx0 + k * 256; if (i < n) d[i] = s[i]; }
        }
        return;
    }
    int n = tab.n[a];
    const void* s = tab.src[a];
    float* d = base + tab.off[a];
    if (flag) {
        const float* sf = (const float*)s;
#pragma unroll
        for (int k = 0; k < 8; k++) { int i = idx0 + k * 256; if (i < n) d[i] = sf[i]; }
    } else {
        const bf16* sb = (const bf16*)s;
#pragma unroll
        for (int k = 0; k < 8; k++) { int i = idx0 + k * 256; if (i < n) d[i] = __bfloat162float(sb[i]); }
    }
}

// ---------------- K_trans: weights [K][N] -> bf16 [N][K] ---------------------
__global__ __launch_bounds__(256) void k_trans(TransTab tab, short* __restrict__ wt,
                                               const int* __restrict__ flagp)
{
    int a = blockIdx.z;
    int Kd = tab.K[a], Nd = tab.N[a];
    int n0 = blockIdx.x * 32, k0 = blockIdx.y * 32;
    if (n0 >= Nd || k0 >= Kd) return;
    int flag = *flagp;
    __shared__ short tile[32][33];
    int t = threadIdx.x, c = t & 31, r4 = t >> 5;
    const void* s = tab.src[a];
#pragma unroll
    for (int p = 0; p < 4; p++) {
        int r = r4 + p * 8;
        short v;
        if (flag) v = bf2s(__float2bfloat16(((const float*)s)[(size_t)(k0 + r) * Nd + n0 + c]));
        else      v = ((const short*)s)[(size_t)(k0 + r) * Nd + n0 + c];
        tile[r][c] = v;
    }
    __syncthreads();
    short* dT = wt + tab.off[a];
#pragma unroll
    for (int p = 0; p < 4; p++) {
        int r = r4 + p * 8;
        dT[(size_t)(n0 + r) * Kd + k0 + c] = tile[c][r];
    }
}

// ---------------- K_fill_edge: y=0 pair-map + bitmap, y=1 edge bias ----------
__global__ __launch_bounds__(256) void k_fill_edge(
    const int* __restrict__ src, const int* __restrict__ dst,
    int* __restrict__ pair, unsigned* __restrict__ bits,
    const float* __restrict__ ef, const float* __restrict__ We,
    const float* __restrict__ be, float* __restrict__ ebuf)
{
    __shared__ float w[80], bb[8];
    int tid = threadIdx.x;
    int e = blockIdx.x * 256 + tid;
    if (blockIdx.y == 0) {
        if (e < E_CNT) {
            int s = src[e], d = dst[e];
            atomicMax(&pair[(size_t)s * NN + d], e);         // last-write-wins
            atomicOr(&bits[s * 64 + (d >> 5)], 1u << (d & 31));
            atomicOr(&bits[d * 64 + (s >> 5)], 1u << (s & 31));
        }
        if (e < NN) atomicOr(&bits[e * 64 + (e >> 5)], 1u << (e & 31));
        return;
    }
    if (tid < 80) w[tid] = We[tid];
    if (tid < 8)  bb[tid] = be[tid];
    __syncthreads();
    if (e < E_CNT) {
        float v[10];
#pragma unroll
        for (int t2 = 0; t2 < 10; t2++) v[t2] = ef[e * 10 + t2];
#pragma unroll
        for (int h = 0; h < 8; h++) {
            float s = bb[h];
#pragma unroll
            for (int t2 = 0; t2 < 10; t2++) s += v[t2] * w[t2 * 8 + h];
            ebuf[e * 8 + h] = s;
        }
    }
}

// ---------------- K_qkv3: Q/K/V projections, z selects ----------------------
__global__ __launch_bounds__(256) void k_qkv3(
    const bf16* __restrict__ A,
    const bf16* __restrict__ WqT, const bf16* __restrict__ WkT, const bf16* __restrict__ WvT,
    const float* __restrict__ bq, const float* __restrict__ bk, const float* __restrict__ bv,
    float* __restrict__ Qo, bf16* __restrict__ Kb, bf16* __restrict__ Vb)
{
    int z = blockIdx.z;
    const bf16* BT = (z == 0) ? WqT : (z == 1) ? WkT : WvT;
    const float* bias = (z == 0) ? bq : (z == 1) ? bk : bv;
    __shared__ __align__(16) short As[4 * 64 * 8];
    __shared__ __align__(16) short Bs[4 * 32 * 8];
    int t = threadIdx.x, w = t >> 6, l = t & 63, fr = l & 15, fc = l >> 4;
    int i0 = blockIdx.x * 64, j0 = blockIdx.y * 32;
    int lr = t >> 2, lc = t & 3;
    f32x4 acc0 = {0.f, 0.f, 0.f, 0.f}, acc1 = {0.f, 0.f, 0.f, 0.f};
    const short* ap = (const short*)A + (size_t)(i0 + lr) * D + lc * 8;
    const short* bp = (const short*)BT + (size_t)(j0 + (lr & 31)) * D + lc * 8;
    for (int k0 = 0; k0 < D; k0 += 32) {
        short8 av = *(const short8*)(ap + k0);
        short8 bv2 = {};
        if (t < 128) bv2 = *(const short8*)(bp + k0);
        __syncthreads();
        *(short8*)&As[(lc * 64 + lr) * 8] = av;
        if (t < 128) *(short8*)&Bs[(lc * 32 + lr) * 8] = bv2;
        __syncthreads();
        short8 af  = *(const short8*)&As[(fc * 64 + w * 16 + fr) * 8];
        short8 bf0 = *(const short8*)&Bs[(fc * 32 + fr) * 8];
        short8 bf1 = *(const short8*)&Bs[(fc * 32 + 16 + fr) * 8];
        acc0 = __builtin_amdgcn_mfma_f32_16x16x32_bf16(af, bf0, acc0, 0, 0, 0);
        acc1 = __builtin_amdgcn_mfma_f32_16x16x32_bf16(af, bf1, acc1, 0, 0, 0);
    }
    float bb0 = bias[j0 + fr], bb1 = bias[j0 + 16 + fr];
    int orow = i0 + w * 16 + fc * 4;
    if (z == 0) {
#pragma unroll
        for (int j = 0; j < 4; j++) {
            Qo[(size_t)(orow + j) * D + j0 + fr]      = acc0[j] + bb0;
            Qo[(size_t)(orow + j) * D + j0 + 16 + fr] = acc1[j] + bb1;
        }
    } else {
        bf16* C = (z == 1) ? Kb : Vb;
#pragma unroll
        for (int j = 0; j < 4; j++) {
            C[(size_t)(orow + j) * D + j0 + fr]      = __float2bfloat16(acc0[j] + bb0);
            C[(size_t)(orow + j) * D + j0 + 16 + fr] = __float2bfloat16(acc1[j] + bb1);
        }
    }
}

// ---------------- K_attn: sparse MHA, pair-map bias, scan discovery ----------
__global__ __launch_bounds__(256) void k_attn(
    const float* __restrict__ Q, const bf16* __restrict__ K,
    const bf16* __restrict__ V, const float* __restrict__ eb,
    const int* __restrict__ pair, const unsigned* __restrict__ bits,
    bf16* __restrict__ attn_out)
{
    int i = blockIdx.x;
    int tid = threadIdx.x;
    __shared__ float q[D];
    __shared__ int   nbr[MAXN];
    __shared__ float sc[MAXN][8];
    __shared__ float mh[8], lhi[8];
    __shared__ int   nn_s;
    q[tid] = Q[(size_t)i * D + tid];
    if (tid < 64) {
        unsigned wrd = bits[i * 64 + tid];
        int cnt = __popc(wrd);
        int pre = cnt;
#pragma unroll
        for (int off = 1; off < 64; off <<= 1) {
            int v = __shfl_up(pre, off, 64);
            if (tid >= off) pre += v;
        }
        int pos = pre - cnt;                 // exclusive prefix -> sorted list
        while (wrd) {
            int b = __ffs(wrd) - 1;
            wrd &= wrd - 1;
            if (pos < MAXN) nbr[pos] = tid * 32 + b;
            pos++;
        }
        if (tid == 63) nn_s = (pre < MAXN) ? pre : MAXN;
    }
    __syncthreads();
    int nn = nn_s;
    const short* Ks = (const short*)K;
    const size_t prow = (size_t)i * NN;
    for (int t2 = tid; t2 < nn * 8; t2 += 256) {
        int n = t2 >> 3, h = t2 & 7;
        int j = nbr[n];
        const short8* kr = (const short8*)(Ks + (size_t)j * D + h * 32);
        const float4* qr = (const float4*)(q + h * 32);
        float s = 0.f;
#pragma unroll
        for (int c = 0; c < 4; c++) {
            short8 kv = kr[c];
            float4 q0 = qr[c * 2], q1 = qr[c * 2 + 1];
            s += q0.x * bs2f((unsigned short)kv[0]) + q0.y * bs2f((unsigned short)kv[1])
               + q0.z * bs2f((unsigned short)kv[2]) + q0.w * bs2f((unsigned short)kv[3])
               + q1.x * bs2f((unsigned short)kv[4]) + q1.y * bs2f((unsigned short)kv[5])
               + q1.z * bs2f((unsigned short)kv[6]) + q1.w * bs2f((unsigned short)kv[7]);
        }
        s *= 0.17677669529663687f;
        int e = pair[prow + j];
        if (e >= 0) s += eb[e * 8 + h];
        sc[n][h] = s;
    }
    __syncthreads();
    // stats: 8 heads x 32 lanes (head = tid>>5), shfl within 32-lane group
    {
        int h = tid >> 5, l32 = tid & 31;
        float m = -1e30f;
        for (int n = l32; n < nn; n += 32) m = fmaxf(m, sc[n][h]);
#pragma unroll
        for (int off = 1; off < 32; off <<= 1) m = fmaxf(m, __shfl_xor(m, off, 64));
        float lsum = 0.f;
        for (int n = l32; n < nn; n += 32) lsum += expf(sc[n][h] - m);
#pragma unroll
        for (int off = 1; off < 32; off <<= 1) lsum += __shfl_xor(lsum, off, 64);
        if (l32 == 0) { mh[h] = m; lhi[h] = 1.f / lsum; }
    }
    __syncthreads();
    for (int t2 = tid; t2 < nn * 8; t2 += 256) {
        int n = t2 >> 3, h = t2 & 7;
        sc[n][h] = expf(sc[n][h] - mh[h]);
    }
    __syncthreads();
    // PV: thread owns col tid (head = tid>>5); final scale by 1/l
    int h = tid >> 5;
    const unsigned short* Vu = (const unsigned short*)V;
    float acc = 0.f;
    int n = 0;
    for (; n + 4 <= nn; n += 4) {
        int j0 = nbr[n], j1 = nbr[n + 1], j2 = nbr[n + 2], j3 = nbr[n + 3];
        float p0 = sc[n][h], p1 = sc[n + 1][h], p2 = sc[n + 2][h], p3 = sc[n + 3][h];
        acc += p0 * bs2f(Vu[(size_t)j0 * D + tid]) + p1 * bs2f(Vu[(size_t)j1 * D + tid])
             + p2 * bs2f(Vu[(size_t)j2 * D + tid]) + p3 * bs2f(Vu[(size_t)j3 * D + tid]);
    }
    for (; n < nn; n++) acc += sc[n][h] * bs2f(Vu[(size_t)nbr[n] * D + tid]);
    attn_out[(size_t)i * D + tid] = __float2bfloat16(acc * lhi[h]);
}

// ---------------- K_mega: O-proj+LN1+FFN1+FFN2+LN2, 16 rows/block ------------
__global__ __launch_bounds__(256) void k_mega(
    const bf16* __restrict__ attn_out, const bf16* __restrict__ WoT,
    const float* __restrict__ bo, const float* __restrict__ node_f32,
    const float* __restrict__ n1w, const float* __restrict__ n1b,
    const bf16* __restrict__ W1T, const float* __restrict__ b1,
    const bf16* __restrict__ W2T, const float* __restrict__ b2,
    const float* __restrict__ n2w, const float* __restrict__ n2b,
    const int* __restrict__ flagp,
    float* __restrict__ outf, bf16* __restrict__ outb)
{
    __shared__ __align__(16) short A3[32 * 4 * 16 * 8];   // 32 KB: hid; first 8KB doubles as A1
    __shared__ __align__(16) short A2[8 * 4 * 16 * 8];    // 8 KB: x1 bf16
    __shared__ __align__(16) short Bs[4 * 256 * 8];       // 16 KB: B panel
    __shared__ float Cs[16][257];                         // x1 fp32 (after LN1)
    __shared__ float Cs3[16][257];                        // FFN2 output
    const int t = threadIdx.x;
    const int w = t >> 6, l = t & 63, fr = l & 15, fc = l >> 4;
    const int ar = t >> 2, akc = t & 3;
    const int i0 = blockIdx.x * 16;

    // stage A1 = attn_out rows, chunk-major: flat slot (c*4+s)*16+r
    for (int idx = t; idx < 512; idx += 256) {
        int c = idx >> 6, s = (idx >> 4) & 3, r = idx & 15;
        *(short8*)&A3[idx * 8] =
            *(const short8*)((const short*)attn_out + (size_t)(i0 + r) * D + c * 32 + s * 8);
    }

    f32x4 acc[4];
#pragma unroll
    for (int c = 0; c < 4; c++) acc[c] = {0.f, 0.f, 0.f, 0.f};
    // ---- GEMM1: C1 = A1 @ WoT^T (K=256) ----
    for (int kc = 0; kc < 8; kc++) {
        __syncthreads();
#pragma unroll
        for (int p = 0; p < 4; p++)
            *(short8*)&Bs[(akc * 256 + p * 64 + ar) * 8] =
                *(const short8*)((const short*)WoT + (size_t)(p * 64 + ar) * 256 + kc * 32 + akc * 8);
        __syncthreads();
        short8 af = *(const short8*)&A3[((kc * 4 + fc) * 16 + fr) * 8];
#pragma unroll
        for (int c = 0; c < 4; c++) {
            short8 bfr = *(const short8*)&Bs[(fc * 256 + (w * 4 + c) * 16 + fr) * 8];
            acc[c] = __builtin_amdgcn_mfma_f32_16x16x32_bf16(af, bfr, acc[c], 0, 0, 0);
        }
    }
    __syncthreads();
#pragma unroll
    for (int c = 0; c < 4; c++) {
        int col = (w * 4 + c) * 16 + fr;
        float bb = bo[col];
#pragma unroll
        for (int j = 0; j < 4; j++) Cs[fc * 4 + j][col] = acc[c][j] + bb;
    }
    __syncthreads();
    // ---- LN1 (16 lanes per row) -> Cs (fp32 x1), A2 (bf16 x1) ----
    {
        int r = t >> 4, c0 = t & 15;
        float vb[16];
        float s = 0.f, qq = 0.f;
#pragma unroll
        for (int m = 0; m < 16; m++) {
            int c = c0 + m * 16;
            float v = Cs[r][c] + node_f32[(size_t)(i0 + r) * D + c];
            vb[m] = v; s += v; qq += v * v;
        }
#pragma unroll
        for (int off = 1; off < 16; off <<= 1) {
            s  += __shfl_xor(s, off, 64);
            qq += __shfl_xor(qq, off, 64);
        }
        float mu = s * (1.f / D);
        float var = qq * (1.f / D) - mu * mu;
        float rsd = rsqrtf(var + 1e-5f);
#pragma unroll
        for (int m = 0; m < 16; m++) {
            int c = c0 + m * 16;
            float o = (vb[m] - mu) * rsd * n1w[c] + n1b[c];
            Cs[r][c] = o;
            A2[(((c >> 5) * 4 + ((c >> 3) & 3)) * 16 + r) * 8 + (c & 7)] = f2bs(o);
        }
    }
    // ---- GEMM2: hid = relu(x1 @ W1T^T + b1), 4 col-groups of 256 ----
    for (int cg = 0; cg < 4; cg++) {
#pragma unroll
        for (int c = 0; c < 4; c++) acc[c] = {0.f, 0.f, 0.f, 0.f};
        for (int kc = 0; kc < 8; kc++) {
            __syncthreads();
#pragma unroll
            for (int p = 0; p < 4; p++)
                *(short8*)&Bs[(akc * 256 + p * 64 + ar) * 8] =
                    *(const short8*)((const short*)W1T + (size_t)(cg * 256 + p * 64 + ar) * 256 + kc * 32 + akc * 8);
            __syncthreads();
            short8 af = *(const short8*)&A2[((kc * 4 + fc) * 16 + fr) * 8];
#pragma unroll
            for (int c = 0; c < 4; c++) {
                short8 bfr = *(const short8*)&Bs[(fc * 256 + (w * 4 + c) * 16 + fr) * 8];
                acc[c] = __builtin_amdgcn_mfma_f32_16x16x32_bf16(af, bfr, acc[c], 0, 0, 0);
            }
        }
#pragma unroll
        for (int c = 0; c < 4; c++) {
            int jg = cg * 256 + (w * 4 + c) * 16 + fr;
            float bb = b1[jg];
#pragma unroll
            for (int j = 0; j < 4; j++) {
                float hv = fmaxf(acc[c][j] + bb, 0.f);
                int row = fc * 4 + j;
                A3[(((jg >> 5) * 4 + ((jg >> 3) & 3)) * 16 + row) * 8 + (jg & 7)] = f2bs(hv);
            }
        }
    }
    // ---- GEMM3: C3 = hid @ W2T^T (K=1024) ----
#pragma unroll
    for (int c = 0; c < 4; c++) acc[c] = {0.f, 0.f, 0.f, 0.f};
    for (int kc = 0; kc < 32; kc++) {
        __syncthreads();
#pragma unroll
        for (int p = 0; p < 4; p++)
            *(short8*)&Bs[(akc * 256 + p * 64 + ar) * 8] =
                *(const short8*)((const short*)W2T + (size_t)(p * 64 + ar) * 1024 + kc * 32 + akc * 8);
        __syncthreads();
        short8 af = *(const short8*)&A3[((kc * 4 + fc) * 16 + fr) * 8];
#pragma unroll
        for (int c = 0; c < 4; c++) {
            short8 bfr = *(const short8*)&Bs[(fc * 256 + (w * 4 + c) * 16 + fr) * 8];
            acc[c] = __builtin_amdgcn_mfma_f32_16x16x32_bf16(af, bfr, acc[c], 0, 0, 0);
        }
    }
    __syncthreads();
#pragma unroll
    for (int c = 0; c < 4; c++) {
        int col = (w * 4 + c) * 16 + fr;
        float bb = b2[col];
#pragma unroll
        for (int j = 0; j < 4; j++) Cs3[fc * 4 + j][col] = acc[c][j] + bb;
    }
    __syncthreads();
    // ---- LN2 -> d_out ----
    {
        int r = t >> 4, c0 = t & 15;
        float vb[16];
        float s = 0.f, qq = 0.f;
#pragma unroll
        for (int m = 0; m < 16; m++) {
            int c = c0 + m * 16;
            float v = Cs3[r][c] + Cs[r][c];
            vb[m] = v; s += v; qq += v * v;
        }
#pragma unroll
        for (int off = 1; off < 16; off <<= 1) {
            s  += __shfl_xor(s, off, 64);
            qq += __shfl_xor(qq, off, 64);
        }
        float mu = s * (1.f / D);
        float var = qq * (1.f / D) - mu * mu;
        float rsd = rsqrtf(var + 1e-5f);
        int flag = *flagp;
#pragma unroll
        for (int m = 0; m < 16; m++) {
            int c = c0 + m * 16;
            float o = (vb[m] - mu) * rsd * n2w[c] + n2b[c];
            size_t idx = (size_t)(i0 + r) * D + c;
            if (flag) outf[idx] = o;
            else      outb[idx] = __float2bfloat16(o);
        }
    }
}

extern "C" void kernel_launch(void* const* d_in, const int* in_sizes, int n_in,
                              void* d_out, int out_size, void* d_ws, size_t ws_size,
                              hipStream_t stream)
{
    (void)n_in; (void)out_size; (void)ws_size;
    const int* src = (const int*)d_in[2];
    const int* dst = (const int*)d_in[3];

    char* ws = (char*)d_ws;
    const size_t KB = 1024;
    float*    conv     = (float*)ws;                      // 0 .. 3.5 MB fp32 inputs
    bf16*     node_b16 = (bf16*)(ws + 3584 * KB);         // 1 MB
    short*    wt       = (short*)(ws + 4608 * KB);        // 1.5 MB
    int*      flagp    = (int*)(ws + 6144 * KB);
    unsigned* bits     = (unsigned*)(ws + 6272 * KB);     // 512 KB
    float*    eb       = (float*)(ws + 7168 * KB);        // 1 MB
    float*    Q        = (float*)(ws + 8192 * KB);        // 2 MB
    bf16*     Kb       = (bf16*)(ws + 10240 * KB);        // 1 MB
    bf16*     Vb       = (bf16*)(ws + 11264 * KB);        // 1 MB
    bf16*     attn_out = (bf16*)(ws + 12288 * KB);        // 1 MB
    int*      pair     = (int*)(ws + 16384 * KB);         // 16 MB -> ends 32 MB

    static const int conv_idx[NCONV] = {0, 1, 5, 7, 9, 11, 12, 13, 14, 15, 17, 19, 20, 21};
    ConvTab tab;
    int off = 0;
    for (int a = 0; a < NCONV; a++) {
        int gi = conv_idx[a];
        tab.src[a] = d_in[gi];
        tab.n[a]   = in_sizes[gi];
        tab.off[a] = off;
        off += (in_sizes[gi] + 255) & ~255;
    }
    const float* node_f32 = conv + tab.off[0];
    const float* edge_f32 = conv + tab.off[1];
    const float* fbq  = conv + tab.off[2];
    const float* fbk  = conv + tab.off[3];
    const float* fbv  = conv + tab.off[4];
    const float* fbo  = conv + tab.off[5];
    const float* fWe  = conv + tab.off[6];
    const float* fbe  = conv + tab.off[7];
    const float* fn1w = conv + tab.off[8];
    const float* fn1b = conv + tab.off[9];
    const float* fb1  = conv + tab.off[10];
    const float* fb2  = conv + tab.off[11];
    const float* fn2w = conv + tab.off[12];
    const float* fn2b = conv + tab.off[13];

    TransTab tt;
    const int widx[6] = {4, 6, 8, 10, 16, 18};
    const int wK[6] = {256, 256, 256, 256, 256, 1024};
    const int wN[6] = {256, 256, 256, 256, 1024, 256};
    const int woff[6] = {0, 65536, 131072, 196608, 262144, 524288};
    for (int a = 0; a < 6; a++) { tt.src[a] = d_in[widx[a]]; tt.K[a] = wK[a]; tt.N[a] = wN[a]; tt.off[a] = woff[a]; }
    const bf16* WqT = (const bf16*)(wt + 0);
    const bf16* WkT = (const bf16*)(wt + 65536);
    const bf16* WvT = (const bf16*)(wt + 131072);
    const bf16* WoT = (const bf16*)(wt + 196608);
    const bf16* W1T = (const bf16*)(wt + 262144);
    const bf16* W2T = (const bf16*)(wt + 524288);

    hipMemsetAsync(bits, 0x00, (size_t)NN * 64 * 4, stream);
    hipMemsetAsync(pair, 0xFF, (size_t)NN * NN * 4, stream);   // -1

    k_sniff<<<1, 256, 0, stream>>>((const unsigned short*)d_in[0], flagp);
    k_convert<<<dim3(256, NCONV + 1), 256, 0, stream>>>(tab, conv, node_b16, d_in[0], flagp);
    k_trans<<<dim3(32, 32, 6), 256, 0, stream>>>(tt, wt, flagp);
    k_fill_edge<<<dim3(128, 2), 256, 0, stream>>>(src, dst, pair, bits,
                                                  edge_f32, fWe, fbe, eb);
    k_qkv3<<<dim3(32, 8, 3), 256, 0, stream>>>(node_b16, WqT, WkT, WvT, fbq, fbk, fbv, Q, Kb, Vb);
    k_attn<<<NN, 256, 0, stream>>>(Q, Kb, Vb, eb, pair, bits, attn_out);
    k_mega<<<128, 256, 0, stream>>>(attn_out, WoT, fbo, node_f32, fn1w, fn1b,
                                    W1T, fb1, W2T, fb2, fn2w, fn2b, flagp,
                                    (float*)d_out, (bf16*)d_out);
}

// Round 7
// 167.297 us; speedup vs baseline: 1.9125x; 1.1267x over previous
//
#include <hip/hip_runtime.h>
#include <hip/hip_bf16.h>

#define NN 2048
#define E_CNT 32768
#define D 256
#define DFF 1024
#define MAXN 256
#define NCONV 14

typedef __hip_bfloat16 bf16;
typedef __attribute__((ext_vector_type(8))) short short8;
typedef __attribute__((ext_vector_type(4))) float f32x4;

__device__ __forceinline__ short bf2s(bf16 x) { union { bf16 b; short s; } u; u.b = x; return u.s; }
__device__ __forceinline__ float bs2f(unsigned short v) { return __uint_as_float(((unsigned)v) << 16); }

struct ConvTab { const void* src[NCONV]; int n[NCONV]; int off[NCONV]; };
struct TransTab { const void* src[6]; int K[6]; int N[6]; int off[6]; };

// ---------------- K_sniff: bf16 vs fp32 staging detector ---------------------
__global__ __launch_bounds__(256) void k_sniff(const unsigned short* __restrict__ p,
                                               int* __restrict__ flagp)
{
    int tid = threadIdx.x;
    int cnt = 0;
    for (int t = tid; t < 2048; t += 256) {
        float f = __uint_as_float(((unsigned)p[t]) << 16);
        if (!(fabsf(f) < 1000.f)) cnt++;
    }
#pragma unroll
    for (int off = 32; off > 0; off >>= 1) cnt += __shfl_down(cnt, off, 64);
    __shared__ int s[4];
    if ((tid & 63) == 0) s[tid >> 6] = cnt;
    __syncthreads();
    if (tid == 0) *flagp = (s[0] + s[1] + s[2] + s[3] > 64) ? 1 : 0;
}

// ---------------- K_convert: float inputs -> fp32 ws; entry NCONV = node->bf16
__global__ __launch_bounds__(256) void k_convert(ConvTab tab, float* __restrict__ base,
                                                 bf16* __restrict__ nb,
                                                 const void* __restrict__ nodesrc,
                                                 const int* __restrict__ flagp)
{
    int a = blockIdx.y;
    int flag = *flagp;
    int idx0 = blockIdx.x * 2048 + threadIdx.x;
    if (a == NCONV) {
        const int n = NN * D;
        if (flag) {
            const float* s = (const float*)nodesrc;
#pragma unroll
            for (int k = 0; k < 8; k++) { int i = idx0 + k * 256; if (i < n) nb[i] = __float2bfloat16(s[i]); }
        } else {
            const short* s = (const short*)nodesrc;
            short* d = (short*)nb;
#pragma unroll
            for (int k = 0; k < 8; k++) { int i = idx0 + k * 256; if (i < n) d[i] = s[i]; }
        }
        return;
    }
    int n = tab.n[a];
    const void* s = tab.src[a];
    float* d = base + tab.off[a];
    if (flag) {
        const float* sf = (const float*)s;
#pragma unroll
        for (int k = 0; k < 8; k++) { int i = idx0 + k * 256; if (i < n) d[i] = sf[i]; }
    } else {
        const bf16* sb = (const bf16*)s;
#pragma unroll
        for (int k = 0; k < 8; k++) { int i = idx0 + k * 256; if (i < n) d[i] = __bfloat162float(sb[i]); }
    }
}

// ---------------- K_trans: weights [K][N] -> bf16 [N][K] ---------------------
__global__ __launch_bounds__(256) void k_trans(TransTab tab, short* __restrict__ wt,
                                               const int* __restrict__ flagp)
{
    int a = blockIdx.z;
    int Kd = tab.K[a], Nd = tab.N[a];
    int n0 = blockIdx.x * 32, k0 = blockIdx.y * 32;
    if (n0 >= Nd || k0 >= Kd) return;
    int flag = *flagp;
    __shared__ short tile[32][33];
    int t = threadIdx.x, c = t & 31, r4 = t >> 5;
    const void* s = tab.src[a];
#pragma unroll
    for (int p = 0; p < 4; p++) {
        int r = r4 + p * 8;
        short v;
        if (flag) v = bf2s(__float2bfloat16(((const float*)s)[(size_t)(k0 + r) * Nd + n0 + c]));
        else      v = ((const short*)s)[(size_t)(k0 + r) * Nd + n0 + c];
        tile[r][c] = v;
    }
    __syncthreads();
    short* dT = wt + tab.off[a];
#pragma unroll
    for (int p = 0; p < 4; p++) {
        int r = r4 + p * 8;
        dT[(size_t)(n0 + r) * Kd + k0 + c] = tile[c][r];
    }
}

// ---------------- K_fill_edge: y=0 pair-map + bitmap, y=1 edge bias ----------
__global__ __launch_bounds__(256) void k_fill_edge(
    const int* __restrict__ src, const int* __restrict__ dst,
    int* __restrict__ pair, unsigned* __restrict__ bits,
    const float* __restrict__ ef, const float* __restrict__ We,
    const float* __restrict__ be, float* __restrict__ ebuf)
{
    __shared__ float w[80], bb[8];
    int tid = threadIdx.x;
    int e = blockIdx.x * 256 + tid;
    if (blockIdx.y == 0) {
        if (e < E_CNT) {
            int s = src[e], d = dst[e];
            atomicMax(&pair[(size_t)s * NN + d], e);         // last-write-wins
            atomicOr(&bits[s * 64 + (d >> 5)], 1u << (d & 31));
            atomicOr(&bits[d * 64 + (s >> 5)], 1u << (s & 31));
        }
        if (e < NN) atomicOr(&bits[e * 64 + (e >> 5)], 1u << (e & 31));
        return;
    }
    if (tid < 80) w[tid] = We[tid];
    if (tid < 8)  bb[tid] = be[tid];
    __syncthreads();
    if (e < E_CNT) {
        float v[10];
#pragma unroll
        for (int t2 = 0; t2 < 10; t2++) v[t2] = ef[e * 10 + t2];
#pragma unroll
        for (int h = 0; h < 8; h++) {
            float s = bb[h];
#pragma unroll
            for (int t2 = 0; t2 < 10; t2++) s += v[t2] * w[t2 * 8 + h];
            ebuf[e * 8 + h] = s;
        }
    }
}

// ---------------- K_qkv3: Q/K/V projections, z selects, BK=64 ---------------
__global__ __launch_bounds__(256) void k_qkv3(
    const bf16* __restrict__ A,
    const bf16* __restrict__ WqT, const bf16* __restrict__ WkT, const bf16* __restrict__ WvT,
    const float* __restrict__ bq, const float* __restrict__ bk, const float* __restrict__ bv,
    float* __restrict__ Qo, bf16* __restrict__ Kb, bf16* __restrict__ Vb)
{
    int z = blockIdx.z;
    const bf16* BT = (z == 0) ? WqT : (z == 1) ? WkT : WvT;
    const float* bias = (z == 0) ? bq : (z == 1) ? bk : bv;
    __shared__ __align__(16) short As[2][4 * 64 * 8];
    __shared__ __align__(16) short Bs[2][4 * 32 * 8];
    int t = threadIdx.x, w = t >> 6, l = t & 63, fr = l & 15, fc = l >> 4;
    int i0 = blockIdx.x * 64, j0 = blockIdx.y * 32;
    int lr = t >> 2, lc = t & 3;
    f32x4 acc0 = {0.f, 0.f, 0.f, 0.f}, acc1 = {0.f, 0.f, 0.f, 0.f};
    const short* ap = (const short*)A + (size_t)(i0 + lr) * D + lc * 8;
    const short* bp = (const short*)BT + (size_t)(j0 + (lr & 31)) * D + lc * 8;
    for (int k0 = 0; k0 < D; k0 += 64) {
        short8 av0 = *(const short8*)(ap + k0);
        short8 av1 = *(const short8*)(ap + k0 + 32);
        short8 bv0 = {}, bv1 = {};
        if (t < 128) {
            bv0 = *(const short8*)(bp + k0);
            bv1 = *(const short8*)(bp + k0 + 32);
        }
        __syncthreads();
        *(short8*)&As[0][(lc * 64 + lr) * 8] = av0;
        *(short8*)&As[1][(lc * 64 + lr) * 8] = av1;
        if (t < 128) {
            *(short8*)&Bs[0][(lc * 32 + lr) * 8] = bv0;
            *(short8*)&Bs[1][(lc * 32 + lr) * 8] = bv1;
        }
        __syncthreads();
#pragma unroll
        for (int s = 0; s < 2; s++) {
            short8 af  = *(const short8*)&As[s][(fc * 64 + w * 16 + fr) * 8];
            short8 bf0 = *(const short8*)&Bs[s][(fc * 32 + fr) * 8];
            short8 bf1 = *(const short8*)&Bs[s][(fc * 32 + 16 + fr) * 8];
            acc0 = __builtin_amdgcn_mfma_f32_16x16x32_bf16(af, bf0, acc0, 0, 0, 0);
            acc1 = __builtin_amdgcn_mfma_f32_16x16x32_bf16(af, bf1, acc1, 0, 0, 0);
        }
    }
    float bb0 = bias[j0 + fr], bb1 = bias[j0 + 16 + fr];
    int orow = i0 + w * 16 + fc * 4;
    if (z == 0) {
#pragma unroll
        for (int j = 0; j < 4; j++) {
            Qo[(size_t)(orow + j) * D + j0 + fr]      = acc0[j] + bb0;
            Qo[(size_t)(orow + j) * D + j0 + 16 + fr] = acc1[j] + bb1;
        }
    } else {
        bf16* C = (z == 1) ? Kb : Vb;
#pragma unroll
        for (int j = 0; j < 4; j++) {
            C[(size_t)(orow + j) * D + j0 + fr]      = __float2bfloat16(acc0[j] + bb0);
            C[(size_t)(orow + j) * D + j0 + 16 + fr] = __float2bfloat16(acc1[j] + bb1);
        }
    }
}

// ---------------- K_gemm: C = A@BT^T + bias, tile 64x32, BK=64 ---------------
template<int EPI>   // 0: fp32 out (+bias), 1: bf16 out (+bias, relu)
__global__ __launch_bounds__(256) void k_gemm(
    const bf16* __restrict__ A, const bf16* __restrict__ BT,
    const float* __restrict__ bias, void* __restrict__ Cp, int N, int K)
{
    __shared__ __align__(16) short As[2][4 * 64 * 8];
    __shared__ __align__(16) short Bs[2][4 * 32 * 8];
    int t = threadIdx.x;
    int w = t >> 6, l = t & 63;
    int fr = l & 15, fc = l >> 4;
    int i0 = blockIdx.x * 64, j0 = blockIdx.y * 32;
    int lr = t >> 2, lc = t & 3;
    f32x4 acc0 = {0.f, 0.f, 0.f, 0.f}, acc1 = {0.f, 0.f, 0.f, 0.f};
    const short* ap = (const short*)A + (size_t)(i0 + lr) * K + lc * 8;
    const short* bp = (const short*)BT + (size_t)(j0 + (lr & 31)) * K + lc * 8;
    for (int k0 = 0; k0 < K; k0 += 64) {
        short8 av0 = *(const short8*)(ap + k0);
        short8 av1 = *(const short8*)(ap + k0 + 32);
        short8 bv0 = {}, bv1 = {};
        if (t < 128) {
            bv0 = *(const short8*)(bp + k0);
            bv1 = *(const short8*)(bp + k0 + 32);
        }
        __syncthreads();
        *(short8*)&As[0][(lc * 64 + lr) * 8] = av0;
        *(short8*)&As[1][(lc * 64 + lr) * 8] = av1;
        if (t < 128) {
            *(short8*)&Bs[0][(lc * 32 + lr) * 8] = bv0;
            *(short8*)&Bs[1][(lc * 32 + lr) * 8] = bv1;
        }
        __syncthreads();
#pragma unroll
        for (int s = 0; s < 2; s++) {
            short8 af  = *(const short8*)&As[s][(fc * 64 + w * 16 + fr) * 8];
            short8 bf0 = *(const short8*)&Bs[s][(fc * 32 + fr) * 8];
            short8 bf1 = *(const short8*)&Bs[s][(fc * 32 + 16 + fr) * 8];
            acc0 = __builtin_amdgcn_mfma_f32_16x16x32_bf16(af, bf0, acc0, 0, 0, 0);
            acc1 = __builtin_amdgcn_mfma_f32_16x16x32_bf16(af, bf1, acc1, 0, 0, 0);
        }
    }
    float bb0 = bias[j0 + fr];
    float bb1 = bias[j0 + 16 + fr];
    int orow = i0 + w * 16 + fc * 4;
    if (EPI == 0) {
        float* C = (float*)Cp;
#pragma unroll
        for (int j = 0; j < 4; j++) {
            C[(size_t)(orow + j) * N + j0 + fr]      = acc0[j] + bb0;
            C[(size_t)(orow + j) * N + j0 + 16 + fr] = acc1[j] + bb1;
        }
    } else {
        bf16* C = (bf16*)Cp;
#pragma unroll
        for (int j = 0; j < 4; j++) {
            C[(size_t)(orow + j) * N + j0 + fr]      = __float2bfloat16(fmaxf(acc0[j] + bb0, 0.f));
            C[(size_t)(orow + j) * N + j0 + 16 + fr] = __float2bfloat16(fmaxf(acc1[j] + bb1, 0.f));
        }
    }
}

// ---------------- K_attn: sparse MHA, eid hoisted to LDS ---------------------
__global__ __launch_bounds__(256) void k_attn(
    const float* __restrict__ Q, const bf16* __restrict__ K,
    const bf16* __restrict__ V, const float* __restrict__ eb,
    const int* __restrict__ pair, const unsigned* __restrict__ bits,
    bf16* __restrict__ attn_out)
{
    int i = blockIdx.x;
    int tid = threadIdx.x;
    __shared__ float q[D];
    __shared__ int   nbr[MAXN];
    __shared__ int   eid[MAXN];
    __shared__ float sc[MAXN][8];
    __shared__ float mh[8], lhi[8];
    __shared__ int   nn_s;
    q[tid] = Q[(size_t)i * D + tid];
    if (tid < 64) {
        unsigned wrd = bits[i * 64 + tid];
        int cnt = __popc(wrd);
        int pre = cnt;
#pragma unroll
        for (int off = 1; off < 64; off <<= 1) {
            int v = __shfl_up(pre, off, 64);
            if (tid >= off) pre += v;
        }
        int pos = pre - cnt;                 // exclusive prefix -> sorted list
        while (wrd) {
            int b = __ffs(wrd) - 1;
            wrd &= wrd - 1;
            if (pos < MAXN) nbr[pos] = tid * 32 + b;
            pos++;
        }
        if (tid == 63) nn_s = (pre < MAXN) ? pre : MAXN;
    }
    __syncthreads();
    int nn = nn_s;
    const size_t prow = (size_t)i * NN;
    for (int n = tid; n < nn; n += 256) eid[n] = pair[prow + nbr[n]];
    __syncthreads();
    const short* Ks = (const short*)K;
    for (int t2 = tid; t2 < nn * 8; t2 += 256) {
        int n = t2 >> 3, h = t2 & 7;
        int j = nbr[n];
        const short8* kr = (const short8*)(Ks + (size_t)j * D + h * 32);
        const float4* qr = (const float4*)(q + h * 32);
        float s = 0.f;
#pragma unroll
        for (int c = 0; c < 4; c++) {
            short8 kv = kr[c];
            float4 q0 = qr[c * 2], q1 = qr[c * 2 + 1];
            s += q0.x * bs2f((unsigned short)kv[0]) + q0.y * bs2f((unsigned short)kv[1])
               + q0.z * bs2f((unsigned short)kv[2]) + q0.w * bs2f((unsigned short)kv[3])
               + q1.x * bs2f((unsigned short)kv[4]) + q1.y * bs2f((unsigned short)kv[5])
               + q1.z * bs2f((unsigned short)kv[6]) + q1.w * bs2f((unsigned short)kv[7]);
        }
        s *= 0.17677669529663687f;
        int e = eid[n];
        if (e >= 0) s += eb[e * 8 + h];
        sc[n][h] = s;
    }
    __syncthreads();
    // stats: 8 heads x 32 lanes (head = tid>>5)
    {
        int h = tid >> 5, l32 = tid & 31;
        float m = -1e30f;
        for (int n = l32; n < nn; n += 32) m = fmaxf(m, sc[n][h]);
#pragma unroll
        for (int off = 1; off < 32; off <<= 1) m = fmaxf(m, __shfl_xor(m, off, 64));
        float lsum = 0.f;
        for (int n = l32; n < nn; n += 32) lsum += __expf(sc[n][h] - m);
#pragma unroll
        for (int off = 1; off < 32; off <<= 1) lsum += __shfl_xor(lsum, off, 64);
        if (l32 == 0) { mh[h] = m; lhi[h] = 1.f / lsum; }
    }
    __syncthreads();
    for (int t2 = tid; t2 < nn * 8; t2 += 256) {
        int n = t2 >> 3, h = t2 & 7;
        sc[n][h] = __expf(sc[n][h] - mh[h]);
    }
    __syncthreads();
    // PV: thread owns col tid (head = tid>>5); final scale by 1/l
    int h = tid >> 5;
    const unsigned short* Vu = (const unsigned short*)V;
    float acc = 0.f;
    int n = 0;
    for (; n + 4 <= nn; n += 4) {
        int j0 = nbr[n], j1 = nbr[n + 1], j2 = nbr[n + 2], j3 = nbr[n + 3];
        float p0 = sc[n][h], p1 = sc[n + 1][h], p2 = sc[n + 2][h], p3 = sc[n + 3][h];
        acc += p0 * bs2f(Vu[(size_t)j0 * D + tid]) + p1 * bs2f(Vu[(size_t)j1 * D + tid])
             + p2 * bs2f(Vu[(size_t)j2 * D + tid]) + p3 * bs2f(Vu[(size_t)j3 * D + tid]);
    }
    for (; n < nn; n++) acc += sc[n][h] * bs2f(Vu[(size_t)nbr[n] * D + tid]);
    attn_out[(size_t)i * D + tid] = __float2bfloat16(acc * lhi[h]);
}

// ---------------- K_ln: wave-per-row, g + res -> LN -> outputs ---------------
template<int MODE>   // 0: write xf(fp32)+xb(bf16); 1: write d_out per flag
__global__ __launch_bounds__(256) void k_ln(
    const float* __restrict__ g, const float* __restrict__ res,
    const float* __restrict__ w, const float* __restrict__ b,
    float* __restrict__ xf, bf16* __restrict__ xb, const int* __restrict__ flagp)
{
    int row = blockIdx.x * 4 + (threadIdx.x >> 6);
    int l = threadIdx.x & 63;
    size_t base = (size_t)row * D + l * 4;
    float4 gv = *(const float4*)(g + base);
    float4 rv = *(const float4*)(res + base);
    float v0 = gv.x + rv.x, v1 = gv.y + rv.y, v2 = gv.z + rv.z, v3 = gv.w + rv.w;
    float s = v0 + v1 + v2 + v3;
    float q = v0 * v0 + v1 * v1 + v2 * v2 + v3 * v3;
#pragma unroll
    for (int off = 32; off > 0; off >>= 1) {
        s += __shfl_xor(s, off, 64);
        q += __shfl_xor(q, off, 64);
    }
    float mu  = s * (1.f / D);
    float var = q * (1.f / D) - mu * mu;
    float rs  = rsqrtf(var + 1e-5f);
    float4 wv = *(const float4*)(w + l * 4);
    float4 bv = *(const float4*)(b + l * 4);
    float o0 = (v0 - mu) * rs * wv.x + bv.x;
    float o1 = (v1 - mu) * rs * wv.y + bv.y;
    float o2 = (v2 - mu) * rs * wv.z + bv.z;
    float o3 = (v3 - mu) * rs * wv.w + bv.w;
    if (MODE == 0) {
        float4 o; o.x = o0; o.y = o1; o.z = o2; o.w = o3;
        *(float4*)(xf + base) = o;
        xb[base + 0] = __float2bfloat16(o0);
        xb[base + 1] = __float2bfloat16(o1);
        xb[base + 2] = __float2bfloat16(o2);
        xb[base + 3] = __float2bfloat16(o3);
    } else {
        if (*flagp) {
            float4 o; o.x = o0; o.y = o1; o.z = o2; o.w = o3;
            *(float4*)(xf + base) = o;
        } else {
            xb[base + 0] = __float2bfloat16(o0);
            xb[base + 1] = __float2bfloat16(o1);
            xb[base + 2] = __float2bfloat16(o2);
            xb[base + 3] = __float2bfloat16(o3);
        }
    }
}

extern "C" void kernel_launch(void* const* d_in, const int* in_sizes, int n_in,
                              void* d_out, int out_size, void* d_ws, size_t ws_size,
                              hipStream_t stream)
{
    (void)n_in; (void)out_size; (void)ws_size;
    const int* src = (const int*)d_in[2];
    const int* dst = (const int*)d_in[3];

    char* ws = (char*)d_ws;
    const size_t KB = 1024;
    float*    conv     = (float*)ws;                      // 0 .. 3.5 MB fp32 inputs
    bf16*     node_b16 = (bf16*)(ws + 3584 * KB);         // 1 MB
    short*    wt       = (short*)(ws + 4608 * KB);        // 1.5 MB
    int*      flagp    = (int*)(ws + 6144 * KB);
    unsigned* bits     = (unsigned*)(ws + 6272 * KB);     // 512 KB
    float*    eb       = (float*)(ws + 7168 * KB);        // 1 MB
    float*    Q        = (float*)(ws + 8192 * KB);        // 2 MB
    bf16*     Kb       = (bf16*)(ws + 10240 * KB);        // 1 MB
    bf16*     Vb       = (bf16*)(ws + 11264 * KB);        // 1 MB
    bf16*     attn_out = (bf16*)(ws + 12288 * KB);        // 1 MB
    float*    x1f      = (float*)(ws + 13312 * KB);       // 2 MB
    bf16*     x1b      = (bf16*)(ws + 15360 * KB);        // 1 MB
    int*      pair     = (int*)(ws + 16384 * KB);         // 16 MB
    float*    g2       = (float*)(ws + 32768 * KB);       // 2 MB
    bf16*     hid      = (bf16*)(ws + 34816 * KB);        // 4 MB
    float*    g4       = (float*)(ws + 38912 * KB);       // 2 MB -> ends 40 MB

    static const int conv_idx[NCONV] = {0, 1, 5, 7, 9, 11, 12, 13, 14, 15, 17, 19, 20, 21};
    ConvTab tab;
    int off = 0;
    for (int a = 0; a < NCONV; a++) {
        int gi = conv_idx[a];
        tab.src[a] = d_in[gi];
        tab.n[a]   = in_sizes[gi];
        tab.off[a] = off;
        off += (in_sizes[gi] + 255) & ~255;
    }
    const float* node_f32 = conv + tab.off[0];
    const float* edge_f32 = conv + tab.off[1];
    const float* fbq  = conv + tab.off[2];
    const float* fbk  = conv + tab.off[3];
    const float* fbv  = conv + tab.off[4];
    const float* fbo  = conv + tab.off[5];
    const float* fWe  = conv + tab.off[6];
    const float* fbe  = conv + tab.off[7];
    const float* fn1w = conv + tab.off[8];
    const float* fn1b = conv + tab.off[9];
    const float* fb1  = conv + tab.off[10];
    const float* fb2  = conv + tab.off[11];
    const float* fn2w = conv + tab.off[12];
    const float* fn2b = conv + tab.off[13];

    TransTab tt;
    const int widx[6] = {4, 6, 8, 10, 16, 18};
    const int wK[6] = {256, 256, 256, 256, 256, 1024};
    const int wN[6] = {256, 256, 256, 256, 1024, 256};
    const int woff[6] = {0, 65536, 131072, 196608, 262144, 524288};
    for (int a = 0; a < 6; a++) { tt.src[a] = d_in[widx[a]]; tt.K[a] = wK[a]; tt.N[a] = wN[a]; tt.off[a] = woff[a]; }
    const bf16* WqT = (const bf16*)(wt + 0);
    const bf16* WkT = (const bf16*)(wt + 65536);
    const bf16* WvT = (const bf16*)(wt + 131072);
    const bf16* WoT = (const bf16*)(wt + 196608);
    const bf16* W1T = (const bf16*)(wt + 262144);
    const bf16* W2T = (const bf16*)(wt + 524288);

    hipMemsetAsync(bits, 0x00, (size_t)NN * 64 * 4, stream);
    hipMemsetAsync(pair, 0xFF, (size_t)NN * NN * 4, stream);   // -1

    k_sniff<<<1, 256, 0, stream>>>((const unsigned short*)d_in[0], flagp);
    k_convert<<<dim3(256, NCONV + 1), 256, 0, stream>>>(tab, conv, node_b16, d_in[0], flagp);
    k_trans<<<dim3(32, 32, 6), 256, 0, stream>>>(tt, wt, flagp);
    k_fill_edge<<<dim3(128, 2), 256, 0, stream>>>(src, dst, pair, bits,
                                                  edge_f32, fWe, fbe, eb);
    k_qkv3<<<dim3(32, 8, 3), 256, 0, stream>>>(node_b16, WqT, WkT, WvT, fbq, fbk, fbv, Q, Kb, Vb);
    k_attn<<<NN, 256, 0, stream>>>(Q, Kb, Vb, eb, pair, bits, attn_out);

    k_gemm<0><<<dim3(32, 8), 256, 0, stream>>>(attn_out, WoT, fbo, g2, D, D);
    k_ln<0><<<NN / 4, 256, 0, stream>>>(g2, node_f32, fn1w, fn1b, x1f, x1b, flagp);
    k_gemm<1><<<dim3(32, 32), 256, 0, stream>>>(x1b, W1T, fb1, hid, DFF, D);
    k_gemm<0><<<dim3(32, 8), 256, 0, stream>>>(hid, W2T, fb2, g4, D, DFF);
    k_ln<1><<<NN / 4, 256, 0, stream>>>(g4, x1f, fn2w, fn2b, (float*)d_out, (bf16*)d_out, flagp);
}